// Round 7
// baseline (343.856 us; speedup 1.0000x reference)
//
#include <hip/hip_runtime.h>
#include <hip/hip_bf16.h>
#include <math.h>

typedef __bf16 bf16x8 __attribute__((ext_vector_type(8)));
typedef __bf16 bf16x4 __attribute__((ext_vector_type(4)));
typedef unsigned short u16x8 __attribute__((ext_vector_type(8)));
typedef float f32x4 __attribute__((ext_vector_type(4)));

#define EP_QKV 0
#define EP_GELU 1
#define EP_RES 2

static __device__ __forceinline__ unsigned short f2bf(float x) {
  unsigned int u = __float_as_uint(x);
  unsigned int r = (u + 0x7fffu + ((u >> 16) & 1u)) >> 16;  // RNE
  return (unsigned short)r;
}

// pack two fp32 -> two bf16 (truncation) in ONE v_perm_b32
static __device__ __forceinline__ unsigned int pkbf(float lo, float hi) {
  return __builtin_amdgcn_perm(__float_as_uint(hi), __float_as_uint(lo), 0x07060302);
}

static __device__ __forceinline__ void async16(const void* g, void* l) {
  __builtin_amdgcn_global_load_lds((__attribute__((address_space(1))) void*)g,
                                   (__attribute__((address_space(3))) void*)l, 16, 0, 0);
}

// ---------------- weight convert + transpose: fp32 [K][N] -> bf16 [N][K] ----
__global__ __launch_bounds__(256) void wt_transpose(const float* __restrict__ in,
                                                    unsigned short* __restrict__ out,
                                                    int K, int N) {
  __shared__ float tile[32][33];
  const int n0 = blockIdx.x * 32;
  const int k0 = blockIdx.y * 32;
  const int tx = threadIdx.x;  // 0..31
  const int ty = threadIdx.y;  // 0..7
  #pragma unroll
  for (int i = ty; i < 32; i += 8)
    tile[i][tx] = in[(size_t)(k0 + i) * N + n0 + tx];
  __syncthreads();
  #pragma unroll
  for (int i = ty; i < 32; i += 8)
    out[(size_t)(n0 + i) * K + k0 + tx] = f2bf(tile[tx][i]);
}

// ---------------- layernorm fp32 -> bf16 -----------------------------------
__global__ __launch_bounds__(256) void ln_kernel(const float* __restrict__ x,
                                                 const float* __restrict__ g,
                                                 const float* __restrict__ b,
                                                 unsigned short* __restrict__ outp) {
  const int row = blockIdx.x;
  const int tid = threadIdx.x;
  const int wave = tid >> 6, lane = tid & 63;
  const float4 v = ((const float4*)(x + (size_t)row * 1024))[tid];
  float s = v.x + v.y + v.z + v.w;
  #pragma unroll
  for (int i = 1; i < 64; i <<= 1) s += __shfl_xor(s, i);
  __shared__ float red[4];
  if (lane == 0) red[wave] = s;
  __syncthreads();
  const float mean = (red[0] + red[1] + red[2] + red[3]) * (1.f / 1024.f);
  const float dx = v.x - mean, dy = v.y - mean, dz = v.z - mean, dw = v.w - mean;
  float ss = dx * dx + dy * dy + dz * dz + dw * dw;
  #pragma unroll
  for (int i = 1; i < 64; i <<= 1) ss += __shfl_xor(ss, i);
  __syncthreads();
  if (lane == 0) red[wave] = ss;
  __syncthreads();
  const float var = (red[0] + red[1] + red[2] + red[3]) * (1.f / 1024.f);
  const float inv = rsqrtf(var + 1e-6f);
  const float4 gv = ((const float4*)g)[tid];
  const float4 bv = ((const float4*)b)[tid];
  ushort4 o;
  o.x = f2bf(dx * inv * gv.x + bv.x);
  o.y = f2bf(dy * inv * gv.y + bv.y);
  o.z = f2bf(dz * inv * gv.z + bv.z);
  o.w = f2bf(dw * inv * gv.w + bv.w);
  ((ushort4*)(outp + (size_t)row * 1024))[tid] = o;
}

// ---------------- GEMM: C = A[M,K] * BT[N,K]^T + bias ----------------------
// Two schedules:
//  DBUF=false (m97-style): single 32KB LDS stage, issue -> sync -> compute ->
//    sync. Latency hidden by CU-level block overlap: __launch_bounds__(256,3)
//    => 3 blocks/CU. (256,4) was tried and REGRESSED ~13us: 128-VGPR cap is
//    below the ~130 live set -> spills. Keep 3.
//  DBUF=true: double-buffered issue-ahead pipeline (for TN=64 kernels whose
//    grids only supply 2 blocks/CU — block overlap can't hide latency there).
// XCD-rectangle block swizzle in both: per-XCD L2 working set ~4-6 MB.
template <int TN, int BK, bool DBUF>
__global__ __launch_bounds__(256, DBUF ? 2 : 3) void gemm_kernel(
    const unsigned short* __restrict__ A,   // bf16 [M][K]
    const unsigned short* __restrict__ BT,  // bf16 [N][K]
    const float* __restrict__ bias,         // [N]
    int M, int N, int K, int mode,
    void* __restrict__ outp, const float* __restrict__ res) {
  constexpr int AM = (TN == 128) ? 4 : 2;   // m-subtiles per wave
  constexpr int ACH = BK / 16;              // A chunks per lane per stage
  constexpr int BCH = TN * BK / 2048;       // B chunks per lane per stage
  constexpr int CPR = BK / 8;               // 16B chunks per LDS row
  constexpr int ABYTES = 256 * BK;          // A stage bytes (128 rows)
  constexpr int BBYTES = TN * BK * 2;
  constexpr int NBUF = DBUF ? 2 : 1;
  __shared__ __align__(16) char smem[NBUF * (ABYTES + BBYTES)];

  const int tid = threadIdx.x;
  const int wave = tid >> 6, lane = tid & 63;
  const int quad = lane >> 4, l16 = lane & 15;
  const int wm = (TN == 128) ? (wave >> 1) : wave;
  const int wn = (TN == 128) ? (wave & 1) : 0;

  // XCD-rectangle swizzle (requires nbm%4==0, nbn%2==0, grid%8==0)
  const int nbm = M >> 7, nbn = N / TN;
  const int lin = blockIdx.y * gridDim.x + blockIdx.x;
  const int g = lin & 7, idx = lin >> 3;
  const int gm = nbm >> 2, gn = nbn >> 1;
  const int bm = (g & 3) * gm + (idx % gm);
  const int bn = (g >> 2) * gn + (idx / gm);
  const int row_m = bm * 128, row_n = bn * TN;

  int ar[ACH], ac[ACH];
  #pragma unroll
  for (int i = 0; i < ACH; ++i) {
    const int c = wave * (64 * ACH) + i * 64 + lane;
    ar[i] = c / CPR;
    ac[i] = ((c % CPR) ^ (ar[i] & (CPR - 1))) * 8;
  }
  int br[BCH], bc[BCH];
  #pragma unroll
  for (int i = 0; i < BCH; ++i) {
    const int c = wave * (64 * BCH) + i * 64 + lane;
    br[i] = c / CPR;
    bc[i] = ((c % CPR) ^ (br[i] & (CPR - 1))) * 8;
  }

  const unsigned short* Ag = A + (size_t)row_m * K;
  const unsigned short* Bg = BT + (size_t)row_n * K;

  const f32x4 z = {0.f, 0.f, 0.f, 0.f};
  f32x4 acc[AM][4];
  #pragma unroll
  for (int i = 0; i < AM; ++i)
    #pragma unroll
    for (int j = 0; j < 4; ++j) acc[i][j] = z;

  auto issue = [&](int kt, int b) {
    unsigned short* As = (unsigned short*)(smem + b * ABYTES);
    unsigned short* Bs = (unsigned short*)(smem + NBUF * ABYTES + b * BBYTES);
    #pragma unroll
    for (int i = 0; i < ACH; ++i)
      async16(Ag + (size_t)ar[i] * K + kt + ac[i], As + wave * (ACH * 512) + i * 512);
    #pragma unroll
    for (int i = 0; i < BCH; ++i)
      async16(Bg + (size_t)br[i] * K + kt + bc[i], Bs + wave * (BCH * 512) + i * 512);
  };

  auto computeTile = [&](int b) {
    const unsigned short* As = (const unsigned short*)(smem + b * ABYTES);
    const unsigned short* Bs = (const unsigned short*)(smem + NBUF * ABYTES + b * BBYTES);
    #pragma unroll
    for (int h = 0; h < BK / 32; ++h) {
      bf16x8 af[AM], bfv[4];
      #pragma unroll
      for (int t = 0; t < AM; ++t) {
        const int row = wm * (AM * 16) + t * 16 + l16;
        const int ch = (h * 4 + quad) ^ (row & (CPR - 1));
        af[t] = *(const bf16x8*)(As + row * BK + ch * 8);
      }
      #pragma unroll
      for (int t = 0; t < 4; ++t) {
        const int row = wn * 64 + t * 16 + l16;
        const int ch = (h * 4 + quad) ^ (row & (CPR - 1));
        bfv[t] = *(const bf16x8*)(Bs + row * BK + ch * 8);
      }
      #pragma unroll
      for (int tm = 0; tm < AM; ++tm)
        #pragma unroll
        for (int tn = 0; tn < 4; ++tn)
          acc[tm][tn] = __builtin_amdgcn_mfma_f32_16x16x32_bf16(af[tm], bfv[tn], acc[tm][tn], 0, 0, 0);
    }
  };

  if constexpr (DBUF) {
    issue(0, 0);
    for (int kt = 0; kt < K; kt += BK) {
      const int b = (kt / BK) & 1;
      __syncthreads();  // drains issue(kt) — issued a full compute-phase ago
      if (kt + BK < K) issue(kt + BK, b ^ 1);
      computeTile(b);
    }
  } else {
    for (int kt = 0; kt < K; kt += BK) {
      issue(kt, 0);
      __syncthreads();  // implicit vmcnt(0) drain: stage resident
      computeTile(0);
      __syncthreads();  // all waves done reading before next overwrite
    }
  }

  // epilogue: C/D layout col = l16, row = quad*4 + reg
  #pragma unroll
  for (int tn = 0; tn < 4; ++tn) {
    const int col = row_n + wn * 64 + tn * 16 + l16;
    const float bv = bias[col];
    #pragma unroll
    for (int tm = 0; tm < AM; ++tm) {
      const int rbase = row_m + wm * (AM * 16) + tm * 16 + quad * 4;
      float v[4];
      #pragma unroll
      for (int r = 0; r < 4; ++r) v[r] = acc[tm][tn][r] + bv;
      if (mode == EP_QKV) {
        unsigned short* outw = (unsigned short*)outp;
        const int which = col >> 10;
        const int h = (col >> 6) & 15, d = col & 63;
        const int bb = rbase >> 11, n = rbase & 2047;
        const size_t bh = (size_t)(bb * 16 + h);
        if (which == 0) {
          // Q pre-scaled by 0.125*log2(e) so softmax can use raw v_exp_f32
          #pragma unroll
          for (int r = 0; r < 4; ++r)
            outw[(bh * 2048 + n + r) * 64 + d] = f2bf(v[r] * 0.18033688011112043f);
        } else if (which == 1) {
          #pragma unroll
          for (int r = 0; r < 4; ++r)
            outw[4194304ull + (bh * 2048 + n + r) * 64 + d] = f2bf(v[r]);
        } else {
          uint2 o;
          o.x = pkbf(v[0], v[1]);
          o.y = pkbf(v[2], v[3]);
          *(uint2*)(outw + 8388608ull + (bh * 64 + d) * 2048 + n) = o;
        }
      } else if (mode == EP_GELU) {
        #pragma unroll
        for (int r = 0; r < 4; ++r) {
          const float u = v[r];
          const float c = 1.5957691216f * fmaf(0.044715f * u * u, u, u);
          const float e = __expf(c);
          const float gl = u - __fdividef(u, e + 1.0f);
          ((unsigned short*)outp)[(size_t)(rbase + r) * N + col] = f2bf(gl);
        }
      } else {  // EP_RES
        #pragma unroll
        for (int r = 0; r < 4; ++r)
          ((float*)outp)[(size_t)(rbase + r) * N + col] =
              res[(size_t)(rbase + r) * N + col] + v[r];
      }
    }
  }
}

// ---------------- flash attention: q-split waves, KVBLK=64, 4 blocks/CU ----
// Each wave owns 16 COMPLETE q-rows (q0 + wave*16..+15) against ALL keys of
// the tile: no cross-wave accumulator reduction, epilogue is a quad-shuffle
// of lsum + direct store. KVBLK=64 -> LDS 24KB (2x8K K dbuf + 8K V) -> 4
// blocks/CU -> the 1024-block grid runs as ONE clean generation (key-split's
// 48KB gave 3/CU = 768+256 straggler tail). K/V LDS tiles now genuinely
// shared by all 4 waves. Per tile: sync -> issueV(t),issueK(t+1) ->
// QK+softmax -> {vmcnt(2);barrier} -> PV (counted vmcnt keeps K(t+1) in
// flight across the mid barrier; V latency hides under QK+softmax).
__global__ __launch_bounds__(256, 4) void attn_kernel(
    const unsigned short* __restrict__ Q,   // [BH][2048][64] (scaled .125*log2e)
    const unsigned short* __restrict__ Kb,  // [BH][2048][64]
    const unsigned short* __restrict__ VT,  // [BH][64][2048]
    unsigned short* __restrict__ outp) {    // [B*2048][1024]
  __shared__ __align__(16) char smem[24576];
  unsigned short* Ks = (unsigned short*)smem;            // 2x [64][64] swz8 (8KB each)
  unsigned short* Vs = (unsigned short*)(smem + 16384);  // 1x [64 d][64 key] swz8 (8KB)

  const int tid = threadIdx.x;
  const int wave = tid >> 6, lane = tid & 63;
  const int quad = lane >> 4, l16 = lane & 15;

  // bhi-clustered XCD swizzle: XCD g (= lin&7, round-robin dispatch) owns
  // bhi in {4g..4g+3} -> per-XCD K+V working set ~1-1.5MB, L2-resident.
  // Requires grid == dim3(32, 32).
  const int lin = blockIdx.y * gridDim.x + blockIdx.x;
  const int g = lin & 7, idx = lin >> 3;        // g: XCD, idx: 0..127
  const int bhi = g * 4 + (idx >> 5);           // 4 bhi per XCD
  const int q0 = (idx & 31) * 64;               // 32 q-blocks per bhi

  const unsigned short* Qg = Q + ((size_t)bhi * 2048 + q0) * 64;
  const unsigned short* Kg = Kb + (size_t)bhi * 2048 * 64;
  const unsigned short* Vg = VT + (size_t)bhi * 64 * 2048;

  // staging: 8KB tile = 512 16B-chunks = 2 chunks/lane. Pre-swizzled global
  // source (chunk ci of row rr holds global chunk ci^(rr&7)) + linear LDS.
  const unsigned short* kp[2];
  const unsigned short* vp[2];
  #pragma unroll
  for (int i = 0; i < 2; ++i) {
    const int c = wave * 128 + i * 64 + lane;   // chunk id 0..511
    const int rr = c >> 3, cc = ((c & 7) ^ (rr & 7)) * 8;
    kp[i] = Kg + (size_t)rr * 64 + cc;          // K row rr, 8-key swz chunk
    vp[i] = Vg + (size_t)rr * 2048 + cc;        // V d-row rr, 8-key swz chunk
  }

  auto issueK = [&](int b) {
    unsigned short* Kd = Ks + b * 4096;
    #pragma unroll
    for (int i = 0; i < 2; ++i) async16(kp[i], Kd + wave * 1024 + i * 512);
    #pragma unroll
    for (int i = 0; i < 2; ++i) kp[i] += 4096;  // next 64 K rows
  };
  auto issueV = [&]() {
    #pragma unroll
    for (int i = 0; i < 2; ++i) async16(vp[i], Vs + wave * 1024 + i * 512);
    #pragma unroll
    for (int i = 0; i < 2; ++i) vp[i] += 64;    // next 64 keys
  };

  issueK(0);

  // Q fragments straight from global (L2-warm): wave's 16 q-rows.
  bf16x8 qb[2];
  #pragma unroll
  for (int h = 0; h < 2; ++h)
    qb[h] = *(const bf16x8*)(Qg + (wave * 16 + l16) * 64 + (h * 4 + quad) * 8);

  const f32x4 z = {0.f, 0.f, 0.f, 0.f};
  f32x4 acc[4];
  #pragma unroll
  for (int i = 0; i < 4; ++i) acc[i] = z;
  float lsum = 0.f;

  const int swk = l16 & 7;

  bf16x8 pb[2];
  auto computeQK = [&](int b) {
    const unsigned short* Ksb = Ks + b * 4096;
    f32x4 s[4];
    #pragma unroll
    for (int gi = 0; gi < 4; ++gi) s[gi] = z;
    __builtin_amdgcn_s_setprio(1);
    #pragma unroll
    for (int h = 0; h < 2; ++h) {
      const int ch = (h * 4 + quad) ^ swk;
      #pragma unroll
      for (int gi = 0; gi < 4; ++gi) {
        // key = gi*16 + l16 (row&7 == l16&7 since gi*16 % 8 == 0)
        bf16x8 kf = *(const bf16x8*)(Ksb + (gi * 16 + l16) * 64 + ch * 8);
        s[gi] = __builtin_amdgcn_mfma_f32_16x16x32_bf16(kf, qb[h], s[gi], 0, 0, 0);
      }
    }
    __builtin_amdgcn_s_setprio(0);
    // softmax: s[gi][r] = S[key = gi*16 + quad*4 + r, q = l16-of-wave-group]
    #pragma unroll
    for (int j = 0; j < 2; ++j) {
      union { unsigned int d[4]; bf16x8 b; } cv;
      float p0[4], p1[4];
      float ls = 0.f;
      #pragma unroll
      for (int r = 0; r < 4; ++r) {
        p0[r] = __builtin_amdgcn_exp2f(s[2 * j][r]);
        p1[r] = __builtin_amdgcn_exp2f(s[2 * j + 1][r]);
        ls += p0[r] + p1[r];
      }
      cv.d[0] = pkbf(p0[0], p0[1]);
      cv.d[1] = pkbf(p0[2], p0[3]);
      cv.d[2] = pkbf(p1[0], p1[1]);
      cv.d[3] = pkbf(p1[2], p1[3]);
      lsum += ls;
      pb[j] = cv.b;  // slots: keys 32j + quad*4 + {0..3}, 32j+16+quad*4+{0..3}
    }
  };

  auto computePV = [&]() {
    __builtin_amdgcn_s_setprio(1);
    #pragma unroll
    for (int mt = 0; mt < 4; ++mt) {
      const int d = mt * 16 + l16;
      const int sub = (quad & 1) * 4;
      const int qh = quad >> 1;
      #pragma unroll
      for (int j = 0; j < 2; ++j) {
        // vf k-slot quad*8+e must hold V[d, key matching pb[j] slot e]:
        // e<4 -> keys 32j+quad*4+e  (16B chunk 4j+qh, 8B half quad&1)
        // e>=4 -> keys 32j+16+quad*4+(e-4) (chunk 4j+2+qh)
        bf16x4 vA = *(const bf16x4*)(Vs + d * 64 + ((4 * j + qh) ^ (d & 7)) * 8 + sub);
        bf16x4 vB = *(const bf16x4*)(Vs + d * 64 + ((4 * j + 2 + qh) ^ (d & 7)) * 8 + sub);
        bf16x8 vf = __builtin_shufflevector(vA, vB, 0, 1, 2, 3, 4, 5, 6, 7);
        acc[mt] = __builtin_amdgcn_mfma_f32_16x16x32_bf16(vf, pb[j], acc[mt], 0, 0, 0);
      }
    }
    __builtin_amdgcn_s_setprio(0);
  };

  for (int t = 0; t < 32; ++t) {
    __syncthreads();            // K(t) resident; all waves done with Vs(t-1)
    issueV();                   // 2 loads/wave -> Vs
    issueK((t + 1) & 1);        // 2 loads/wave -> other K buffer (t=31: harmless
                                // in-bounds prefetch of the adjacent region)
    computeQK(t & 1);
    // wait the 2 V loads only; K(t+1) prefetch stays in flight across barrier
    asm volatile("s_waitcnt vmcnt(2) lgkmcnt(0)\n\ts_barrier" ::: "memory");
    computePV();
  }

  // epilogue: wave owns its q-rows completely -> quad-reduce lsum, store.
  float ls = lsum;
  ls += __shfl_xor(ls, 16);
  ls += __shfl_xor(ls, 32);
  const float linv = 1.0f / ls;
  const int b = bhi >> 4, h = bhi & 15;
  const int qrow = q0 + wave * 16 + l16;
  #pragma unroll
  for (int mt = 0; mt < 4; ++mt) {
    uint2 ov;
    ov.x = pkbf(acc[mt][0] * linv, acc[mt][1] * linv);
    ov.y = pkbf(acc[mt][2] * linv, acc[mt][3] * linv);
    *(uint2*)(outp + (size_t)(b * 2048 + qrow) * 1024 + h * 64 + mt * 16 + quad * 4) = ov;
  }
}

// ---------------- launch -----------------------------------------------------
extern "C" void kernel_launch(void* const* d_in, const int* in_sizes, int n_in,
                              void* d_out, int out_size, void* d_ws, size_t ws_size,
                              hipStream_t stream) {
  (void)in_sizes; (void)n_in; (void)out_size; (void)ws_size;
  const float* x      = (const float*)d_in[0];
  const float* ln1_g  = (const float*)d_in[1];
  const float* ln1_b  = (const float*)d_in[2];
  const float* w_qkv  = (const float*)d_in[3];
  const float* b_qkv  = (const float*)d_in[4];
  const float* w_proj = (const float*)d_in[5];
  const float* b_proj = (const float*)d_in[6];
  const float* ln2_g  = (const float*)d_in[7];
  const float* ln2_b  = (const float*)d_in[8];
  const float* w_fc1  = (const float*)d_in[9];
  const float* b_fc1  = (const float*)d_in[10];
  const float* w_fc2  = (const float*)d_in[11];
  const float* b_fc2  = (const float*)d_in[12];

  char* ws = (char*)d_ws;
  unsigned short* wqkvT  = (unsigned short*)(ws + 0);
  unsigned short* wprojT = (unsigned short*)(ws + 6291456);
  unsigned short* wfc1T  = (unsigned short*)(ws + 8388608);
  unsigned short* wfc2T  = (unsigned short*)(ws + 16777216);
  unsigned short* lnb    = (unsigned short*)(ws + 25165824);
  unsigned short* qkvb   = (unsigned short*)(ws + 33554432);
  unsigned short* attnb  = (unsigned short*)(ws + 58720256);
  float*          x2     = (float*)(ws + 67108864);
  unsigned short* hbuf   = qkvb;  // fc1 out aliases dead qkv region

  dim3 tb(32, 8);
  wt_transpose<<<dim3(96, 32), tb, 0, stream>>>(w_qkv, wqkvT, 1024, 3072);
  wt_transpose<<<dim3(32, 32), tb, 0, stream>>>(w_proj, wprojT, 1024, 1024);
  wt_transpose<<<dim3(128, 32), tb, 0, stream>>>(w_fc1, wfc1T, 1024, 4096);
  wt_transpose<<<dim3(32, 128), tb, 0, stream>>>(w_fc2, wfc2T, 4096, 1024);

  ln_kernel<<<4096, 256, 0, stream>>>(x, ln1_g, ln1_b, lnb);

  gemm_kernel<128, 64, false><<<dim3(24, 32), 256, 0, stream>>>(lnb, wqkvT, b_qkv, 4096, 3072, 1024,
                                                                EP_QKV, (void*)qkvb, nullptr);

  attn_kernel<<<dim3(32, 32), 256, 0, stream>>>(qkvb, qkvb + 4194304, qkvb + 8388608, attnb);

  gemm_kernel<64, 64, true><<<dim3(16, 32), 256, 0, stream>>>(attnb, wprojT, b_proj, 4096, 1024, 1024,
                                                              EP_RES, (void*)x2, x);

  ln_kernel<<<4096, 256, 0, stream>>>(x2, ln2_g, ln2_b, lnb);

  gemm_kernel<128, 64, false><<<dim3(32, 32), 256, 0, stream>>>(lnb, wfc1T, b_fc1, 4096, 4096, 1024,
                                                                EP_GELU, (void*)hbuf, nullptr);

  gemm_kernel<64, 64, true><<<dim3(16, 32), 256, 0, stream>>>(hbuf, wfc2T, b_fc2, 4096, 1024, 4096,
                                                              EP_RES, d_out, x2);
}

// Round 8
// 333.840 us; speedup vs baseline: 1.0300x; 1.0300x over previous
//
#include <hip/hip_runtime.h>
#include <hip/hip_bf16.h>
#include <math.h>

typedef __bf16 bf16x8 __attribute__((ext_vector_type(8)));
typedef __bf16 bf16x4 __attribute__((ext_vector_type(4)));
typedef unsigned short u16x8 __attribute__((ext_vector_type(8)));
typedef float f32x4 __attribute__((ext_vector_type(4)));

#define EP_QKV 0
#define EP_GELU 1
#define EP_RES 2

static __device__ __forceinline__ unsigned short f2bf(float x) {
  unsigned int u = __float_as_uint(x);
  unsigned int r = (u + 0x7fffu + ((u >> 16) & 1u)) >> 16;  // RNE
  return (unsigned short)r;
}

// pack two fp32 -> two bf16 (truncation) in ONE v_perm_b32
static __device__ __forceinline__ unsigned int pkbf(float lo, float hi) {
  return __builtin_amdgcn_perm(__float_as_uint(hi), __float_as_uint(lo), 0x07060302);
}

static __device__ __forceinline__ void async16(const void* g, void* l) {
  __builtin_amdgcn_global_load_lds((__attribute__((address_space(1))) void*)g,
                                   (__attribute__((address_space(3))) void*)l, 16, 0, 0);
}

// ---------------- weight convert + transpose: fp32 [K][N] -> bf16 [N][K] ----
__global__ __launch_bounds__(256) void wt_transpose(const float* __restrict__ in,
                                                    unsigned short* __restrict__ out,
                                                    int K, int N) {
  __shared__ float tile[32][33];
  const int n0 = blockIdx.x * 32;
  const int k0 = blockIdx.y * 32;
  const int tx = threadIdx.x;  // 0..31
  const int ty = threadIdx.y;  // 0..7
  #pragma unroll
  for (int i = ty; i < 32; i += 8)
    tile[i][tx] = in[(size_t)(k0 + i) * N + n0 + tx];
  __syncthreads();
  #pragma unroll
  for (int i = ty; i < 32; i += 8)
    out[(size_t)(n0 + i) * K + k0 + tx] = f2bf(tile[tx][i]);
}

// ---------------- layernorm fp32 -> bf16 -----------------------------------
__global__ __launch_bounds__(256) void ln_kernel(const float* __restrict__ x,
                                                 const float* __restrict__ g,
                                                 const float* __restrict__ b,
                                                 unsigned short* __restrict__ outp) {
  const int row = blockIdx.x;
  const int tid = threadIdx.x;
  const int wave = tid >> 6, lane = tid & 63;
  const float4 v = ((const float4*)(x + (size_t)row * 1024))[tid];
  float s = v.x + v.y + v.z + v.w;
  #pragma unroll
  for (int i = 1; i < 64; i <<= 1) s += __shfl_xor(s, i);
  __shared__ float red[4];
  if (lane == 0) red[wave] = s;
  __syncthreads();
  const float mean = (red[0] + red[1] + red[2] + red[3]) * (1.f / 1024.f);
  const float dx = v.x - mean, dy = v.y - mean, dz = v.z - mean, dw = v.w - mean;
  float ss = dx * dx + dy * dy + dz * dz + dw * dw;
  #pragma unroll
  for (int i = 1; i < 64; i <<= 1) ss += __shfl_xor(ss, i);
  __syncthreads();
  if (lane == 0) red[wave] = ss;
  __syncthreads();
  const float var = (red[0] + red[1] + red[2] + red[3]) * (1.f / 1024.f);
  const float inv = rsqrtf(var + 1e-6f);
  const float4 gv = ((const float4*)g)[tid];
  const float4 bv = ((const float4*)b)[tid];
  ushort4 o;
  o.x = f2bf(dx * inv * gv.x + bv.x);
  o.y = f2bf(dy * inv * gv.y + bv.y);
  o.z = f2bf(dz * inv * gv.z + bv.z);
  o.w = f2bf(dw * inv * gv.w + bv.w);
  ((ushort4*)(outp + (size_t)row * 1024))[tid] = o;
}

// ---------------- GEMM: C = A[M,K] * BT[N,K]^T + bias ----------------------
// MODE is now a TEMPLATE param: dead epilogues are eliminated, so e.g. the
// fc1 (EP_GELU) instantiation no longer carries EP_QKV's address math in its
// register allocation. MINW = min waves/SIMD (launch_bounds): fc1 runs at 4
// (128-VGPR cap, viable only with DCE'd epilogue) so its 1024-block grid is
// fully co-resident; qkv stays 3 (768 blocks = exactly 3/CU); DBUF kernels
// stay 2 (grid-limited).
//  DBUF=false (m97-style): single 32KB LDS stage, issue -> sync -> compute ->
//    sync; latency hidden by CU-level block overlap.
//  DBUF=true: double-buffered issue-ahead pipeline (TN=64 kernels, 2/CU).
// XCD-rectangle block swizzle in both: per-XCD L2 working set ~4-6 MB.
template <int TN, int BK, bool DBUF, int MODE, int MINW>
__global__ __launch_bounds__(256, MINW) void gemm_kernel(
    const unsigned short* __restrict__ A,   // bf16 [M][K]
    const unsigned short* __restrict__ BT,  // bf16 [N][K]
    const float* __restrict__ bias,         // [N]
    int M, int N, int K,
    void* __restrict__ outp, const float* __restrict__ res) {
  constexpr int AM = (TN == 128) ? 4 : 2;   // m-subtiles per wave
  constexpr int ACH = BK / 16;              // A chunks per lane per stage
  constexpr int BCH = TN * BK / 2048;       // B chunks per lane per stage
  constexpr int CPR = BK / 8;               // 16B chunks per LDS row
  constexpr int ABYTES = 256 * BK;          // A stage bytes (128 rows)
  constexpr int BBYTES = TN * BK * 2;
  constexpr int NBUF = DBUF ? 2 : 1;
  __shared__ __align__(16) char smem[NBUF * (ABYTES + BBYTES)];

  const int tid = threadIdx.x;
  const int wave = tid >> 6, lane = tid & 63;
  const int quad = lane >> 4, l16 = lane & 15;
  const int wm = (TN == 128) ? (wave >> 1) : wave;
  const int wn = (TN == 128) ? (wave & 1) : 0;

  // XCD-rectangle swizzle (requires nbm%4==0, nbn%2==0, grid%8==0)
  const int nbm = M >> 7, nbn = N / TN;
  const int lin = blockIdx.y * gridDim.x + blockIdx.x;
  const int g = lin & 7, idx = lin >> 3;
  const int gm = nbm >> 2, gn = nbn >> 1;
  const int bm = (g & 3) * gm + (idx % gm);
  const int bn = (g >> 2) * gn + (idx / gm);
  const int row_m = bm * 128, row_n = bn * TN;

  int ar[ACH], ac[ACH];
  #pragma unroll
  for (int i = 0; i < ACH; ++i) {
    const int c = wave * (64 * ACH) + i * 64 + lane;
    ar[i] = c / CPR;
    ac[i] = ((c % CPR) ^ (ar[i] & (CPR - 1))) * 8;
  }
  int br[BCH], bc[BCH];
  #pragma unroll
  for (int i = 0; i < BCH; ++i) {
    const int c = wave * (64 * BCH) + i * 64 + lane;
    br[i] = c / CPR;
    bc[i] = ((c % CPR) ^ (br[i] & (CPR - 1))) * 8;
  }

  const unsigned short* Ag = A + (size_t)row_m * K;
  const unsigned short* Bg = BT + (size_t)row_n * K;

  const f32x4 z = {0.f, 0.f, 0.f, 0.f};
  f32x4 acc[AM][4];
  #pragma unroll
  for (int i = 0; i < AM; ++i)
    #pragma unroll
    for (int j = 0; j < 4; ++j) acc[i][j] = z;

  auto issue = [&](int kt, int b) {
    unsigned short* As = (unsigned short*)(smem + b * ABYTES);
    unsigned short* Bs = (unsigned short*)(smem + NBUF * ABYTES + b * BBYTES);
    #pragma unroll
    for (int i = 0; i < ACH; ++i)
      async16(Ag + (size_t)ar[i] * K + kt + ac[i], As + wave * (ACH * 512) + i * 512);
    #pragma unroll
    for (int i = 0; i < BCH; ++i)
      async16(Bg + (size_t)br[i] * K + kt + bc[i], Bs + wave * (BCH * 512) + i * 512);
  };

  auto computeTile = [&](int b) {
    const unsigned short* As = (const unsigned short*)(smem + b * ABYTES);
    const unsigned short* Bs = (const unsigned short*)(smem + NBUF * ABYTES + b * BBYTES);
    #pragma unroll
    for (int h = 0; h < BK / 32; ++h) {
      bf16x8 af[AM], bfv[4];
      #pragma unroll
      for (int t = 0; t < AM; ++t) {
        const int row = wm * (AM * 16) + t * 16 + l16;
        const int ch = (h * 4 + quad) ^ (row & (CPR - 1));
        af[t] = *(const bf16x8*)(As + row * BK + ch * 8);
      }
      #pragma unroll
      for (int t = 0; t < 4; ++t) {
        const int row = wn * 64 + t * 16 + l16;
        const int ch = (h * 4 + quad) ^ (row & (CPR - 1));
        bfv[t] = *(const bf16x8*)(Bs + row * BK + ch * 8);
      }
      #pragma unroll
      for (int tm = 0; tm < AM; ++tm)
        #pragma unroll
        for (int tn = 0; tn < 4; ++tn)
          acc[tm][tn] = __builtin_amdgcn_mfma_f32_16x16x32_bf16(af[tm], bfv[tn], acc[tm][tn], 0, 0, 0);
    }
  };

  if constexpr (DBUF) {
    issue(0, 0);
    for (int kt = 0; kt < K; kt += BK) {
      const int b = (kt / BK) & 1;
      __syncthreads();  // drains issue(kt) — issued a full compute-phase ago
      if (kt + BK < K) issue(kt + BK, b ^ 1);
      computeTile(b);
    }
  } else {
    for (int kt = 0; kt < K; kt += BK) {
      issue(kt, 0);
      __syncthreads();  // implicit vmcnt(0) drain: stage resident
      computeTile(0);
      __syncthreads();  // all waves done reading before next overwrite
    }
  }

  // epilogue: C/D layout col = l16, row = quad*4 + reg
  #pragma unroll
  for (int tn = 0; tn < 4; ++tn) {
    const int col = row_n + wn * 64 + tn * 16 + l16;
    const float bv = bias[col];
    #pragma unroll
    for (int tm = 0; tm < AM; ++tm) {
      const int rbase = row_m + wm * (AM * 16) + tm * 16 + quad * 4;
      float v[4];
      #pragma unroll
      for (int r = 0; r < 4; ++r) v[r] = acc[tm][tn][r] + bv;
      if constexpr (MODE == EP_QKV) {
        unsigned short* outw = (unsigned short*)outp;
        const int which = col >> 10;
        const int h = (col >> 6) & 15, d = col & 63;
        const int bb = rbase >> 11, n = rbase & 2047;
        const size_t bh = (size_t)(bb * 16 + h);
        if (which == 0) {
          // Q pre-scaled by 0.125*log2(e) so softmax can use raw v_exp_f32
          #pragma unroll
          for (int r = 0; r < 4; ++r)
            outw[(bh * 2048 + n + r) * 64 + d] = f2bf(v[r] * 0.18033688011112043f);
        } else if (which == 1) {
          #pragma unroll
          for (int r = 0; r < 4; ++r)
            outw[4194304ull + (bh * 2048 + n + r) * 64 + d] = f2bf(v[r]);
        } else {
          uint2 o;
          o.x = pkbf(v[0], v[1]);
          o.y = pkbf(v[2], v[3]);
          *(uint2*)(outw + 8388608ull + (bh * 64 + d) * 2048 + n) = o;
        }
      } else if constexpr (MODE == EP_GELU) {
        #pragma unroll
        for (int r = 0; r < 4; ++r) {
          const float u = v[r];
          const float c = 1.5957691216f * fmaf(0.044715f * u * u, u, u);
          const float e = __expf(c);
          const float gl = u - __fdividef(u, e + 1.0f);
          ((unsigned short*)outp)[(size_t)(rbase + r) * N + col] = f2bf(gl);
        }
      } else {  // EP_RES
        #pragma unroll
        for (int r = 0; r < 4; ++r)
          ((float*)outp)[(size_t)(rbase + r) * N + col] =
              res[(size_t)(rbase + r) * N + col] + v[r];
      }
    }
  }
}

// ---------------- flash attention, key-split waves, fixed-shift softmax -----
// (R5 proven version, 53.4us.) LDS 48KB (Q direct-to-reg, single-buffered V).
// Per tile: sync -> issueV(t), issueK(t+1) -> QK+softmax -> {vmcnt(4);barrier}
// -> PV. Counted vmcnt keeps the K(t+1) prefetch in flight across the mid
// barrier; V latency hides under QK+softmax. Key-split (not q-split): each
// K/V LDS fragment feeds 4 MFMA (reuse across 4 q-subtiles) — the R6 q-split
// rebuild dropped reuse to 1 MFMA/read and bank conflicts went 4x, −12%.
// exp2 shift folded out (cancels in o*linv). setprio(1) around MFMA clusters.
__global__ __launch_bounds__(256, 3) void attn_kernel(
    const unsigned short* __restrict__ Q,   // [BH][2048][64] (scaled .125*log2e)
    const unsigned short* __restrict__ Kb,  // [BH][2048][64]
    const unsigned short* __restrict__ VT,  // [BH][64][2048]
    unsigned short* __restrict__ outp) {    // [B*2048][1024]
  __shared__ __align__(16) char smem[49152];
  unsigned short* Ks = (unsigned short*)smem;            // 2x [128][64] swz8 (16KB each)
  unsigned short* Vs = (unsigned short*)(smem + 32768);  // 1x [64][128] swz16 (16KB)

  const int tid = threadIdx.x;
  const int wave = tid >> 6, lane = tid & 63;
  const int quad = lane >> 4, l16 = lane & 15;

  // bhi-clustered XCD swizzle: XCD g (= lin&7, round-robin dispatch) owns
  // bhi in {4g..4g+3} -> per-XCD K+V working set ~1-1.5MB, L2-resident.
  // Requires grid == dim3(32, 32).
  const int lin = blockIdx.y * gridDim.x + blockIdx.x;
  const int g = lin & 7, idx = lin >> 3;        // g: XCD, idx: 0..127
  const int bhi = g * 4 + (idx >> 5);           // 4 bhi per XCD
  const int q0 = (idx & 31) * 64;               // 32 q-blocks per bhi

  const unsigned short* Qg = Q + ((size_t)bhi * 2048 + q0) * 64;
  const unsigned short* Kg = Kb + (size_t)bhi * 2048 * 64;
  const unsigned short* Vg = VT + (size_t)bhi * 64 * 2048;

  const unsigned short* kp[4];
  const unsigned short* vp[4];
  #pragma unroll
  for (int i = 0; i < 4; ++i) {
    const int c = wave * 256 + i * 64 + lane;
    const int krr = c >> 3, kcc = ((c & 7) ^ (krr & 7)) * 8;
    const int vrr = c >> 4, vcc = ((c & 15) ^ (vrr & 15)) * 8;
    kp[i] = Kg + (size_t)krr * 64 + kcc;
    vp[i] = Vg + (size_t)vrr * 2048 + vcc;
  }

  auto issueK = [&](int b) {
    unsigned short* Kd = Ks + b * 8192;
    #pragma unroll
    for (int i = 0; i < 4; ++i) async16(kp[i], Kd + wave * 2048 + i * 512);
    #pragma unroll
    for (int i = 0; i < 4; ++i) kp[i] += 8192;
  };
  auto issueV = [&]() {
    #pragma unroll
    for (int i = 0; i < 4; ++i) async16(vp[i], Vs + wave * 2048 + i * 512);
    #pragma unroll
    for (int i = 0; i < 4; ++i) vp[i] += 128;
  };

  issueK(0);

  // Q fragments straight from global (L2-warm): row nt*16+l16, 16B chunk
  // (h*4+quad) — same data the old LDS stage delivered, minus the round-trip.
  bf16x8 qb[4][2];
  #pragma unroll
  for (int nt = 0; nt < 4; ++nt)
    #pragma unroll
    for (int h = 0; h < 2; ++h)
      qb[nt][h] = *(const bf16x8*)(Qg + (nt * 16 + l16) * 64 + (h * 4 + quad) * 8);

  const f32x4 z = {0.f, 0.f, 0.f, 0.f};
  f32x4 acc[4][4];
  #pragma unroll
  for (int i = 0; i < 4; ++i)
    #pragma unroll
    for (int j = 0; j < 4; ++j) acc[i][j] = z;
  float lsum[4] = {0.f, 0.f, 0.f, 0.f};

  const int rowA = wave * 16 + l16;
  const int rowB = 64 + rowA;
  const int swk = l16 & 7;

  bf16x8 pb[4];
  auto computeQK = [&](int b) {
    const unsigned short* Ksb = Ks + b * 8192;
    f32x4 sA[4], sB[4];
    #pragma unroll
    for (int nt = 0; nt < 4; ++nt) { sA[nt] = z; sB[nt] = z; }
    __builtin_amdgcn_s_setprio(1);
    #pragma unroll
    for (int h = 0; h < 2; ++h) {
      const int ch = (h * 4 + quad) ^ swk;
      bf16x8 kfA = *(const bf16x8*)(Ksb + rowA * 64 + ch * 8);
      bf16x8 kfB = *(const bf16x8*)(Ksb + rowB * 64 + ch * 8);
      #pragma unroll
      for (int nt = 0; nt < 4; ++nt) {
        sA[nt] = __builtin_amdgcn_mfma_f32_16x16x32_bf16(kfA, qb[nt][h], sA[nt], 0, 0, 0);
        sB[nt] = __builtin_amdgcn_mfma_f32_16x16x32_bf16(kfB, qb[nt][h], sB[nt], 0, 0, 0);
      }
    }
    __builtin_amdgcn_s_setprio(0);
    #pragma unroll
    for (int nt = 0; nt < 4; ++nt) {
      union { unsigned int d[4]; bf16x8 b; } cv;
      float pa[4], pv[4];
      float ls = 0.f;
      #pragma unroll
      for (int r = 0; r < 4; ++r) {
        pa[r] = __builtin_amdgcn_exp2f(sA[nt][r]);
        pv[r] = __builtin_amdgcn_exp2f(sB[nt][r]);
        ls += pa[r] + pv[r];
      }
      cv.d[0] = pkbf(pa[0], pa[1]);
      cv.d[1] = pkbf(pa[2], pa[3]);
      cv.d[2] = pkbf(pv[0], pv[1]);
      cv.d[3] = pkbf(pv[2], pv[3]);
      lsum[nt] += ls;
      pb[nt] = cv.b;
    }
  };

  auto computePV = [&]() {
    __builtin_amdgcn_s_setprio(1);
    #pragma unroll
    for (int mt = 0; mt < 4; ++mt) {
      const int d = mt * 16 + l16;
      const int cA = (wave * 2 + (quad >> 1)) ^ (d & 15);
      const int cB = (8 + wave * 2 + (quad >> 1)) ^ (d & 15);
      const int sub = (quad & 1) * 4;
      bf16x4 vA = *(const bf16x4*)(Vs + d * 128 + cA * 8 + sub);
      bf16x4 vB = *(const bf16x4*)(Vs + d * 128 + cB * 8 + sub);
      bf16x8 vf = __builtin_shufflevector(vA, vB, 0, 1, 2, 3, 4, 5, 6, 7);
      #pragma unroll
      for (int nt = 0; nt < 4; ++nt)
        acc[mt][nt] = __builtin_amdgcn_mfma_f32_16x16x32_bf16(vf, pb[nt], acc[mt][nt], 0, 0, 0);
    }
    __builtin_amdgcn_s_setprio(0);
  };

  for (int t = 0; t < 16; ++t) {
    __syncthreads();            // K(t) resident; all waves done with Vs(t-1)
    issueV();                   // 4 loads/wave -> Vs
    issueK((t + 1) & 1);        // 4 loads/wave -> other K buffer (t=15: harmless
                                // in-bounds prefetch of the adjacent region)
    computeQK(t & 1);
    // wait the 4 V loads only; K(t+1) prefetch stays in flight across barrier
    asm volatile("s_waitcnt vmcnt(4) lgkmcnt(0)\n\ts_barrier" ::: "memory");
    computePV();
  }
  __syncthreads();

  float* sc = (float*)smem;
  float* lred = (float*)(smem + 32768);
  #pragma unroll
  for (int nt = 0; nt < 4; ++nt) {
    float ls = lsum[nt];
    ls += __shfl_xor(ls, 16);
    ls += __shfl_xor(ls, 32);
    if (quad == 0) lred[wave * 64 + nt * 16 + l16] = ls;
  }
  if (wave >= 2) {
    float* dst = sc + (wave - 2) * 4096;
    #pragma unroll
    for (int mt = 0; mt < 4; ++mt)
      #pragma unroll
      for (int nt = 0; nt < 4; ++nt)
        *(f32x4*)(dst + (mt * 4 + nt) * 256 + lane * 4) = acc[mt][nt];
  }
  __syncthreads();
  if (wave < 2) {
    const float* src = sc + wave * 4096;
    #pragma unroll
    for (int mt = 0; mt < 4; ++mt)
      #pragma unroll
      for (int nt = 0; nt < 4; ++nt)
        acc[mt][nt] += *(const f32x4*)(src + (mt * 4 + nt) * 256 + lane * 4);
  }
  if (wave == 1) {
    float* dst = sc + 4096;
    #pragma unroll
    for (int mt = 0; mt < 4; ++mt)
      #pragma unroll
      for (int nt = 0; nt < 4; ++nt)
        *(f32x4*)(dst + (mt * 4 + nt) * 256 + lane * 4) = acc[mt][nt];
  }
  __syncthreads();
  if (wave == 0) {
    const float* src = sc + 4096;
    float linv[4];
    #pragma unroll
    for (int nt = 0; nt < 4; ++nt) {
      const int qi = nt * 16 + l16;
      const float l = lred[qi] + lred[64 + qi] + lred[128 + qi] + lred[192 + qi];
      linv[nt] = 1.0f / l;
    }
    const int b = bhi >> 4, h = bhi & 15;
    #pragma unroll
    for (int mt = 0; mt < 4; ++mt)
      #pragma unroll
      for (int nt = 0; nt < 4; ++nt) {
        f32x4 o = acc[mt][nt] + *(const f32x4*)(src + (mt * 4 + nt) * 256 + lane * 4);
        uint2 ov;
        ov.x = pkbf(o[0] * linv[nt], o[1] * linv[nt]);
        ov.y = pkbf(o[2] * linv[nt], o[3] * linv[nt]);
        *(uint2*)(outp + ((size_t)(b * 2048 + q0 + nt * 16 + l16)) * 1024 +
                  h * 64 + mt * 16 + quad * 4) = ov;
      }
  }
}

// ---------------- launch -----------------------------------------------------
extern "C" void kernel_launch(void* const* d_in, const int* in_sizes, int n_in,
                              void* d_out, int out_size, void* d_ws, size_t ws_size,
                              hipStream_t stream) {
  (void)in_sizes; (void)n_in; (void)out_size; (void)ws_size;
  const float* x      = (const float*)d_in[0];
  const float* ln1_g  = (const float*)d_in[1];
  const float* ln1_b  = (const float*)d_in[2];
  const float* w_qkv  = (const float*)d_in[3];
  const float* b_qkv  = (const float*)d_in[4];
  const float* w_proj = (const float*)d_in[5];
  const float* b_proj = (const float*)d_in[6];
  const float* ln2_g  = (const float*)d_in[7];
  const float* ln2_b  = (const float*)d_in[8];
  const float* w_fc1  = (const float*)d_in[9];
  const float* b_fc1  = (const float*)d_in[10];
  const float* w_fc2  = (const float*)d_in[11];
  const float* b_fc2  = (const float*)d_in[12];

  char* ws = (char*)d_ws;
  unsigned short* wqkvT  = (unsigned short*)(ws + 0);
  unsigned short* wprojT = (unsigned short*)(ws + 6291456);
  unsigned short* wfc1T  = (unsigned short*)(ws + 8388608);
  unsigned short* wfc2T  = (unsigned short*)(ws + 16777216);
  unsigned short* lnb    = (unsigned short*)(ws + 25165824);
  unsigned short* qkvb   = (unsigned short*)(ws + 33554432);
  unsigned short* attnb  = (unsigned short*)(ws + 58720256);
  float*          x2     = (float*)(ws + 67108864);
  unsigned short* hbuf   = qkvb;  // fc1 out aliases dead qkv region

  dim3 tb(32, 8);
  wt_transpose<<<dim3(96, 32), tb, 0, stream>>>(w_qkv, wqkvT, 1024, 3072);
  wt_transpose<<<dim3(32, 32), tb, 0, stream>>>(w_proj, wprojT, 1024, 1024);
  wt_transpose<<<dim3(128, 32), tb, 0, stream>>>(w_fc1, wfc1T, 1024, 4096);
  wt_transpose<<<dim3(32, 128), tb, 0, stream>>>(w_fc2, wfc2T, 4096, 1024);

  ln_kernel<<<4096, 256, 0, stream>>>(x, ln1_g, ln1_b, lnb);

  gemm_kernel<128, 64, false, EP_QKV, 3><<<dim3(24, 32), 256, 0, stream>>>(
      lnb, wqkvT, b_qkv, 4096, 3072, 1024, (void*)qkvb, nullptr);

  attn_kernel<<<dim3(32, 32), 256, 0, stream>>>(qkvb, qkvb + 4194304, qkvb + 8388608, attnb);

  gemm_kernel<64, 64, true, EP_RES, 2><<<dim3(16, 32), 256, 0, stream>>>(
      attnb, wprojT, b_proj, 4096, 1024, 1024, (void*)x2, x);

  ln_kernel<<<4096, 256, 0, stream>>>(x2, ln2_g, ln2_b, lnb);

  gemm_kernel<128, 64, false, EP_GELU, 4><<<dim3(32, 32), 256, 0, stream>>>(
      lnb, wfc1T, b_fc1, 4096, 4096, 1024, (void*)hbuf, nullptr);

  gemm_kernel<64, 64, true, EP_RES, 2><<<dim3(16, 32), 256, 0, stream>>>(
      hbuf, wfc2T, b_fc2, 4096, 1024, 4096, d_out, x2);
}

// Round 9
// 316.996 us; speedup vs baseline: 1.0847x; 1.0531x over previous
//
#include <hip/hip_runtime.h>
#include <hip/hip_bf16.h>
#include <math.h>

typedef __bf16 bf16x8 __attribute__((ext_vector_type(8)));
typedef __bf16 bf16x4 __attribute__((ext_vector_type(4)));
typedef unsigned short u16x8 __attribute__((ext_vector_type(8)));
typedef float f32x4 __attribute__((ext_vector_type(4)));

#define EP_QKV 0
#define EP_GELU 1
#define EP_RES 2

static __device__ __forceinline__ unsigned short f2bf(float x) {
  unsigned int u = __float_as_uint(x);
  unsigned int r = (u + 0x7fffu + ((u >> 16) & 1u)) >> 16;  // RNE
  return (unsigned short)r;
}

// pack two fp32 -> two bf16 (truncation) in ONE v_perm_b32
static __device__ __forceinline__ unsigned int pkbf(float lo, float hi) {
  return __builtin_amdgcn_perm(__float_as_uint(hi), __float_as_uint(lo), 0x07060302);
}

static __device__ __forceinline__ void async16(const void* g, void* l) {
  __builtin_amdgcn_global_load_lds((__attribute__((address_space(1))) void*)g,
                                   (__attribute__((address_space(3))) void*)l, 16, 0, 0);
}

// ---------------- weight convert + transpose: fp32 [K][N] -> bf16 [N][K] ----
__global__ __launch_bounds__(256) void wt_transpose(const float* __restrict__ in,
                                                    unsigned short* __restrict__ out,
                                                    int K, int N) {
  __shared__ float tile[32][33];
  const int n0 = blockIdx.x * 32;
  const int k0 = blockIdx.y * 32;
  const int tx = threadIdx.x;  // 0..31
  const int ty = threadIdx.y;  // 0..7
  #pragma unroll
  for (int i = ty; i < 32; i += 8)
    tile[i][tx] = in[(size_t)(k0 + i) * N + n0 + tx];
  __syncthreads();
  #pragma unroll
  for (int i = ty; i < 32; i += 8)
    out[(size_t)(n0 + i) * K + k0 + tx] = f2bf(tile[tx][i]);
}

// ---------------- layernorm fp32 -> bf16 -----------------------------------
__global__ __launch_bounds__(256) void ln_kernel(const float* __restrict__ x,
                                                 const float* __restrict__ g,
                                                 const float* __restrict__ b,
                                                 unsigned short* __restrict__ outp) {
  const int row = blockIdx.x;
  const int tid = threadIdx.x;
  const int wave = tid >> 6, lane = tid & 63;
  const float4 v = ((const float4*)(x + (size_t)row * 1024))[tid];
  float s = v.x + v.y + v.z + v.w;
  #pragma unroll
  for (int i = 1; i < 64; i <<= 1) s += __shfl_xor(s, i);
  __shared__ float red[4];
  if (lane == 0) red[wave] = s;
  __syncthreads();
  const float mean = (red[0] + red[1] + red[2] + red[3]) * (1.f / 1024.f);
  const float dx = v.x - mean, dy = v.y - mean, dz = v.z - mean, dw = v.w - mean;
  float ss = dx * dx + dy * dy + dz * dz + dw * dw;
  #pragma unroll
  for (int i = 1; i < 64; i <<= 1) ss += __shfl_xor(ss, i);
  __syncthreads();
  if (lane == 0) red[wave] = ss;
  __syncthreads();
  const float var = (red[0] + red[1] + red[2] + red[3]) * (1.f / 1024.f);
  const float inv = rsqrtf(var + 1e-6f);
  const float4 gv = ((const float4*)g)[tid];
  const float4 bv = ((const float4*)b)[tid];
  ushort4 o;
  o.x = f2bf(dx * inv * gv.x + bv.x);
  o.y = f2bf(dy * inv * gv.y + bv.y);
  o.z = f2bf(dz * inv * gv.z + bv.z);
  o.w = f2bf(dw * inv * gv.w + bv.w);
  ((ushort4*)(outp + (size_t)row * 1024))[tid] = o;
}

// ---------------- GEMM: C = A[M,K] * BT[N,K]^T + bias ----------------------
// MODE is a TEMPLATE param (dead epilogues eliminated). MINW = min waves/SIMD.
// All single-buffer kernels at MINW=3 (proven value; MINW=4 was neutral-to-
// noise with DCE, and regressed without it — keep 3).
//  DBUF=false (m97-style): single 32KB LDS stage, issue -> sync -> compute ->
//    sync; latency hidden by CU-level block overlap (3 blocks/CU).
//  DBUF=true: double-buffered issue-ahead pipeline (TN=64 kernels, 2/CU).
// XCD-rectangle block swizzle in both: per-XCD L2 working set ~4-6 MB.
template <int TN, int BK, bool DBUF, int MODE, int MINW>
__global__ __launch_bounds__(256, MINW) void gemm_kernel(
    const unsigned short* __restrict__ A,   // bf16 [M][K]
    const unsigned short* __restrict__ BT,  // bf16 [N][K]
    const float* __restrict__ bias,         // [N]
    int M, int N, int K,
    void* __restrict__ outp, const float* __restrict__ res) {
  constexpr int AM = (TN == 128) ? 4 : 2;   // m-subtiles per wave
  constexpr int ACH = BK / 16;              // A chunks per lane per stage
  constexpr int BCH = TN * BK / 2048;       // B chunks per lane per stage
  constexpr int CPR = BK / 8;               // 16B chunks per LDS row
  constexpr int ABYTES = 256 * BK;          // A stage bytes (128 rows)
  constexpr int BBYTES = TN * BK * 2;
  constexpr int NBUF = DBUF ? 2 : 1;
  __shared__ __align__(16) char smem[NBUF * (ABYTES + BBYTES)];

  const int tid = threadIdx.x;
  const int wave = tid >> 6, lane = tid & 63;
  const int quad = lane >> 4, l16 = lane & 15;
  const int wm = (TN == 128) ? (wave >> 1) : wave;
  const int wn = (TN == 128) ? (wave & 1) : 0;

  // XCD-rectangle swizzle (requires nbm%4==0, nbn%2==0, grid%8==0)
  const int nbm = M >> 7, nbn = N / TN;
  const int lin = blockIdx.y * gridDim.x + blockIdx.x;
  const int g = lin & 7, idx = lin >> 3;
  const int gm = nbm >> 2, gn = nbn >> 1;
  const int bm = (g & 3) * gm + (idx % gm);
  const int bn = (g >> 2) * gn + (idx / gm);
  const int row_m = bm * 128, row_n = bn * TN;

  int ar[ACH], ac[ACH];
  #pragma unroll
  for (int i = 0; i < ACH; ++i) {
    const int c = wave * (64 * ACH) + i * 64 + lane;
    ar[i] = c / CPR;
    ac[i] = ((c % CPR) ^ (ar[i] & (CPR - 1))) * 8;
  }
  int br[BCH], bc[BCH];
  #pragma unroll
  for (int i = 0; i < BCH; ++i) {
    const int c = wave * (64 * BCH) + i * 64 + lane;
    br[i] = c / CPR;
    bc[i] = ((c % CPR) ^ (br[i] & (CPR - 1))) * 8;
  }

  const unsigned short* Ag = A + (size_t)row_m * K;
  const unsigned short* Bg = BT + (size_t)row_n * K;

  const f32x4 z = {0.f, 0.f, 0.f, 0.f};
  f32x4 acc[AM][4];
  #pragma unroll
  for (int i = 0; i < AM; ++i)
    #pragma unroll
    for (int j = 0; j < 4; ++j) acc[i][j] = z;

  auto issue = [&](int kt, int b) {
    unsigned short* As = (unsigned short*)(smem + b * ABYTES);
    unsigned short* Bs = (unsigned short*)(smem + NBUF * ABYTES + b * BBYTES);
    #pragma unroll
    for (int i = 0; i < ACH; ++i)
      async16(Ag + (size_t)ar[i] * K + kt + ac[i], As + wave * (ACH * 512) + i * 512);
    #pragma unroll
    for (int i = 0; i < BCH; ++i)
      async16(Bg + (size_t)br[i] * K + kt + bc[i], Bs + wave * (BCH * 512) + i * 512);
  };

  auto computeTile = [&](int b) {
    const unsigned short* As = (const unsigned short*)(smem + b * ABYTES);
    const unsigned short* Bs = (const unsigned short*)(smem + NBUF * ABYTES + b * BBYTES);
    #pragma unroll
    for (int h = 0; h < BK / 32; ++h) {
      bf16x8 af[AM], bfv[4];
      #pragma unroll
      for (int t = 0; t < AM; ++t) {
        const int row = wm * (AM * 16) + t * 16 + l16;
        const int ch = (h * 4 + quad) ^ (row & (CPR - 1));
        af[t] = *(const bf16x8*)(As + row * BK + ch * 8);
      }
      #pragma unroll
      for (int t = 0; t < 4; ++t) {
        const int row = wn * 64 + t * 16 + l16;
        const int ch = (h * 4 + quad) ^ (row & (CPR - 1));
        bfv[t] = *(const bf16x8*)(Bs + row * BK + ch * 8);
      }
      #pragma unroll
      for (int tm = 0; tm < AM; ++tm)
        #pragma unroll
        for (int tn = 0; tn < 4; ++tn)
          acc[tm][tn] = __builtin_amdgcn_mfma_f32_16x16x32_bf16(af[tm], bfv[tn], acc[tm][tn], 0, 0, 0);
    }
  };

  if constexpr (DBUF) {
    issue(0, 0);
    for (int kt = 0; kt < K; kt += BK) {
      const int b = (kt / BK) & 1;
      __syncthreads();  // drains issue(kt) — issued a full compute-phase ago
      if (kt + BK < K) issue(kt + BK, b ^ 1);
      computeTile(b);
    }
  } else {
    for (int kt = 0; kt < K; kt += BK) {
      issue(kt, 0);
      __syncthreads();  // implicit vmcnt(0) drain: stage resident
      computeTile(0);
      __syncthreads();  // all waves done reading before next overwrite
    }
  }

  // epilogue: C/D layout col = l16, row = quad*4 + reg
  #pragma unroll
  for (int tn = 0; tn < 4; ++tn) {
    const int col = row_n + wn * 64 + tn * 16 + l16;
    const float bv = bias[col];
    #pragma unroll
    for (int tm = 0; tm < AM; ++tm) {
      const int rbase = row_m + wm * (AM * 16) + tm * 16 + quad * 4;
      float v[4];
      #pragma unroll
      for (int r = 0; r < 4; ++r) v[r] = acc[tm][tn][r] + bv;
      if constexpr (MODE == EP_QKV) {
        unsigned short* outw = (unsigned short*)outp;
        const int which = col >> 10;
        const int h = (col >> 6) & 15, d = col & 63;
        const int bb = rbase >> 11, n = rbase & 2047;
        const size_t bh = (size_t)(bb * 16 + h);
        if (which == 0) {
          // Q pre-scaled by 0.125*log2(e) so softmax can use raw v_exp_f32
          #pragma unroll
          for (int r = 0; r < 4; ++r)
            outw[(bh * 2048 + n + r) * 64 + d] = f2bf(v[r] * 0.18033688011112043f);
        } else if (which == 1) {
          #pragma unroll
          for (int r = 0; r < 4; ++r)
            outw[4194304ull + (bh * 2048 + n + r) * 64 + d] = f2bf(v[r]);
        } else {
          uint2 o;
          o.x = pkbf(v[0], v[1]);
          o.y = pkbf(v[2], v[3]);
          *(uint2*)(outw + 8388608ull + (bh * 64 + d) * 2048 + n) = o;
        }
      } else if constexpr (MODE == EP_GELU) {
        #pragma unroll
        for (int r = 0; r < 4; ++r) {
          const float u = v[r];
          const float c = 1.5957691216f * fmaf(0.044715f * u * u, u, u);
          const float e = __expf(c);
          const float gl = u - __fdividef(u, e + 1.0f);
          ((unsigned short*)outp)[(size_t)(rbase + r) * N + col] = f2bf(gl);
        }
      } else {  // EP_RES
        #pragma unroll
        for (int r = 0; r < 4; ++r)
          ((float*)outp)[(size_t)(rbase + r) * N + col] =
              res[(size_t)(rbase + r) * N + col] + v[r];
      }
    }
  }
}

// ---------------- flash attention, key-split waves, fixed-shift softmax -----
// LDS 48KB (Q direct-to-reg, single-buffered V). NEW this round: softmax
// moved AFTER the mid-barrier. Per tile:
//   sync -> issueV(t), issueK(t+1) -> QK-MFMA -> {vmcnt(4);barrier} ->
//   softmax -> PV.
// Rationale: the mid-barrier's release = max over waves of arrival; with
// softmax before it, the slowest wave's 32-exp2 chain delayed all 4 waves
// AND the V-wait sat serially before PV. Now barrier skew = MFMA-only
// spread, and the V-wait + skew hide under softmax. Correctness: each wave
// waits its own vmcnt(4) BEFORE s_barrier (all waves' V writes visible
// after), pb precedes PV in program order. sA/sB stay live across the
// barrier (they were live until softmax anyway).
// Key-split retained: each K/V LDS fragment feeds 4 MFMA (R6's q-split
// dropped reuse to 1/read, conflicts 4x, −12%). exp2 shift folded out.
__global__ __launch_bounds__(256, 3) void attn_kernel(
    const unsigned short* __restrict__ Q,   // [BH][2048][64] (scaled .125*log2e)
    const unsigned short* __restrict__ Kb,  // [BH][2048][64]
    const unsigned short* __restrict__ VT,  // [BH][64][2048]
    unsigned short* __restrict__ outp) {    // [B*2048][1024]
  __shared__ __align__(16) char smem[49152];
  unsigned short* Ks = (unsigned short*)smem;            // 2x [128][64] swz8 (16KB each)
  unsigned short* Vs = (unsigned short*)(smem + 32768);  // 1x [64][128] swz16 (16KB)

  const int tid = threadIdx.x;
  const int wave = tid >> 6, lane = tid & 63;
  const int quad = lane >> 4, l16 = lane & 15;

  // bhi-clustered XCD swizzle: XCD g (= lin&7, round-robin dispatch) owns
  // bhi in {4g..4g+3} -> per-XCD K+V working set ~1-1.5MB, L2-resident.
  // Requires grid == dim3(32, 32).
  const int lin = blockIdx.y * gridDim.x + blockIdx.x;
  const int g = lin & 7, idx = lin >> 3;        // g: XCD, idx: 0..127
  const int bhi = g * 4 + (idx >> 5);           // 4 bhi per XCD
  const int q0 = (idx & 31) * 64;               // 32 q-blocks per bhi

  const unsigned short* Qg = Q + ((size_t)bhi * 2048 + q0) * 64;
  const unsigned short* Kg = Kb + (size_t)bhi * 2048 * 64;
  const unsigned short* Vg = VT + (size_t)bhi * 64 * 2048;

  const unsigned short* kp[4];
  const unsigned short* vp[4];
  #pragma unroll
  for (int i = 0; i < 4; ++i) {
    const int c = wave * 256 + i * 64 + lane;
    const int krr = c >> 3, kcc = ((c & 7) ^ (krr & 7)) * 8;
    const int vrr = c >> 4, vcc = ((c & 15) ^ (vrr & 15)) * 8;
    kp[i] = Kg + (size_t)krr * 64 + kcc;
    vp[i] = Vg + (size_t)vrr * 2048 + vcc;
  }

  auto issueK = [&](int b) {
    unsigned short* Kd = Ks + b * 8192;
    #pragma unroll
    for (int i = 0; i < 4; ++i) async16(kp[i], Kd + wave * 2048 + i * 512);
    #pragma unroll
    for (int i = 0; i < 4; ++i) kp[i] += 8192;
  };
  auto issueV = [&]() {
    #pragma unroll
    for (int i = 0; i < 4; ++i) async16(vp[i], Vs + wave * 2048 + i * 512);
    #pragma unroll
    for (int i = 0; i < 4; ++i) vp[i] += 128;
  };

  issueK(0);

  // Q fragments straight from global (L2-warm): row nt*16+l16, 16B chunk
  // (h*4+quad) — same data the old LDS stage delivered, minus the round-trip.
  bf16x8 qb[4][2];
  #pragma unroll
  for (int nt = 0; nt < 4; ++nt)
    #pragma unroll
    for (int h = 0; h < 2; ++h)
      qb[nt][h] = *(const bf16x8*)(Qg + (nt * 16 + l16) * 64 + (h * 4 + quad) * 8);

  const f32x4 z = {0.f, 0.f, 0.f, 0.f};
  f32x4 acc[4][4];
  #pragma unroll
  for (int i = 0; i < 4; ++i)
    #pragma unroll
    for (int j = 0; j < 4; ++j) acc[i][j] = z;
  float lsum[4] = {0.f, 0.f, 0.f, 0.f};

  const int rowA = wave * 16 + l16;
  const int rowB = 64 + rowA;
  const int swk = l16 & 7;

  bf16x8 pb[4];
  f32x4 sA[4], sB[4];

  auto computeQKm = [&](int b) {
    const unsigned short* Ksb = Ks + b * 8192;
    #pragma unroll
    for (int nt = 0; nt < 4; ++nt) { sA[nt] = z; sB[nt] = z; }
    __builtin_amdgcn_s_setprio(1);
    #pragma unroll
    for (int h = 0; h < 2; ++h) {
      const int ch = (h * 4 + quad) ^ swk;
      bf16x8 kfA = *(const bf16x8*)(Ksb + rowA * 64 + ch * 8);
      bf16x8 kfB = *(const bf16x8*)(Ksb + rowB * 64 + ch * 8);
      #pragma unroll
      for (int nt = 0; nt < 4; ++nt) {
        sA[nt] = __builtin_amdgcn_mfma_f32_16x16x32_bf16(kfA, qb[nt][h], sA[nt], 0, 0, 0);
        sB[nt] = __builtin_amdgcn_mfma_f32_16x16x32_bf16(kfB, qb[nt][h], sB[nt], 0, 0, 0);
      }
    }
    __builtin_amdgcn_s_setprio(0);
  };

  auto computeSM = [&]() {
    #pragma unroll
    for (int nt = 0; nt < 4; ++nt) {
      union { unsigned int d[4]; bf16x8 b; } cv;
      float pa[4], pv[4];
      float ls = 0.f;
      #pragma unroll
      for (int r = 0; r < 4; ++r) {
        pa[r] = __builtin_amdgcn_exp2f(sA[nt][r]);
        pv[r] = __builtin_amdgcn_exp2f(sB[nt][r]);
        ls += pa[r] + pv[r];
      }
      cv.d[0] = pkbf(pa[0], pa[1]);
      cv.d[1] = pkbf(pa[2], pa[3]);
      cv.d[2] = pkbf(pv[0], pv[1]);
      cv.d[3] = pkbf(pv[2], pv[3]);
      lsum[nt] += ls;
      pb[nt] = cv.b;
    }
  };

  auto computePV = [&]() {
    __builtin_amdgcn_s_setprio(1);
    #pragma unroll
    for (int mt = 0; mt < 4; ++mt) {
      const int d = mt * 16 + l16;
      const int cA = (wave * 2 + (quad >> 1)) ^ (d & 15);
      const int cB = (8 + wave * 2 + (quad >> 1)) ^ (d & 15);
      const int sub = (quad & 1) * 4;
      bf16x4 vA = *(const bf16x4*)(Vs + d * 128 + cA * 8 + sub);
      bf16x4 vB = *(const bf16x4*)(Vs + d * 128 + cB * 8 + sub);
      bf16x8 vf = __builtin_shufflevector(vA, vB, 0, 1, 2, 3, 4, 5, 6, 7);
      #pragma unroll
      for (int nt = 0; nt < 4; ++nt)
        acc[mt][nt] = __builtin_amdgcn_mfma_f32_16x16x32_bf16(vf, pb[nt], acc[mt][nt], 0, 0, 0);
    }
    __builtin_amdgcn_s_setprio(0);
  };

  for (int t = 0; t < 16; ++t) {
    __syncthreads();            // K(t) resident; all waves done with Vs(t-1)
    issueV();                   // 4 loads/wave -> Vs
    issueK((t + 1) & 1);        // 4 loads/wave -> other K buffer (t=15: harmless
                                // in-bounds prefetch of the adjacent region)
    computeQKm(t & 1);
    // wait own 4 V loads; K(t+1) prefetch stays in flight across the barrier.
    // Barrier arrives right after QK MFMAs (minimal skew); softmax runs after,
    // hiding the residual V latency and inter-wave skew.
    asm volatile("s_waitcnt vmcnt(4) lgkmcnt(0)\n\ts_barrier" ::: "memory");
    computeSM();
    computePV();
  }
  __syncthreads();

  float* sc = (float*)smem;
  float* lred = (float*)(smem + 32768);
  #pragma unroll
  for (int nt = 0; nt < 4; ++nt) {
    float ls = lsum[nt];
    ls += __shfl_xor(ls, 16);
    ls += __shfl_xor(ls, 32);
    if (quad == 0) lred[wave * 64 + nt * 16 + l16] = ls;
  }
  if (wave >= 2) {
    float* dst = sc + (wave - 2) * 4096;
    #pragma unroll
    for (int mt = 0; mt < 4; ++mt)
      #pragma unroll
      for (int nt = 0; nt < 4; ++nt)
        *(f32x4*)(dst + (mt * 4 + nt) * 256 + lane * 4) = acc[mt][nt];
  }
  __syncthreads();
  if (wave < 2) {
    const float* src = sc + wave * 4096;
    #pragma unroll
    for (int mt = 0; mt < 4; ++mt)
      #pragma unroll
      for (int nt = 0; nt < 4; ++nt)
        acc[mt][nt] += *(const f32x4*)(src + (mt * 4 + nt) * 256 + lane * 4);
  }
  if (wave == 1) {
    float* dst = sc + 4096;
    #pragma unroll
    for (int mt = 0; mt < 4; ++mt)
      #pragma unroll
      for (int nt = 0; nt < 4; ++nt)
        *(f32x4*)(dst + (mt * 4 + nt) * 256 + lane * 4) = acc[mt][nt];
  }
  __syncthreads();
  if (wave == 0) {
    const float* src = sc + 4096;
    float linv[4];
    #pragma unroll
    for (int nt = 0; nt < 4; ++nt) {
      const int qi = nt * 16 + l16;
      const float l = lred[qi] + lred[64 + qi] + lred[128 + qi] + lred[192 + qi];
      linv[nt] = 1.0f / l;
    }
    const int b = bhi >> 4, h = bhi & 15;
    #pragma unroll
    for (int mt = 0; mt < 4; ++mt)
      #pragma unroll
      for (int nt = 0; nt < 4; ++nt) {
        f32x4 o = acc[mt][nt] + *(const f32x4*)(src + (mt * 4 + nt) * 256 + lane * 4);
        uint2 ov;
        ov.x = pkbf(o[0] * linv[nt], o[1] * linv[nt]);
        ov.y = pkbf(o[2] * linv[nt], o[3] * linv[nt]);
        *(uint2*)(outp + ((size_t)(b * 2048 + q0 + nt * 16 + l16)) * 1024 +
                  h * 64 + mt * 16 + quad * 4) = ov;
      }
  }
}

// ---------------- launch -----------------------------------------------------
extern "C" void kernel_launch(void* const* d_in, const int* in_sizes, int n_in,
                              void* d_out, int out_size, void* d_ws, size_t ws_size,
                              hipStream_t stream) {
  (void)in_sizes; (void)n_in; (void)out_size; (void)ws_size;
  const float* x      = (const float*)d_in[0];
  const float* ln1_g  = (const float*)d_in[1];
  const float* ln1_b  = (const float*)d_in[2];
  const float* w_qkv  = (const float*)d_in[3];
  const float* b_qkv  = (const float*)d_in[4];
  const float* w_proj = (const float*)d_in[5];
  const float* b_proj = (const float*)d_in[6];
  const float* ln2_g  = (const float*)d_in[7];
  const float* ln2_b  = (const float*)d_in[8];
  const float* w_fc1  = (const float*)d_in[9];
  const float* b_fc1  = (const float*)d_in[10];
  const float* w_fc2  = (const float*)d_in[11];
  const float* b_fc2  = (const float*)d_in[12];

  char* ws = (char*)d_ws;
  unsigned short* wqkvT  = (unsigned short*)(ws + 0);
  unsigned short* wprojT = (unsigned short*)(ws + 6291456);
  unsigned short* wfc1T  = (unsigned short*)(ws + 8388608);
  unsigned short* wfc2T  = (unsigned short*)(ws + 16777216);
  unsigned short* lnb    = (unsigned short*)(ws + 25165824);
  unsigned short* qkvb   = (unsigned short*)(ws + 33554432);
  unsigned short* attnb  = (unsigned short*)(ws + 58720256);
  float*          x2     = (float*)(ws + 67108864);
  unsigned short* hbuf   = qkvb;  // fc1 out aliases dead qkv region

  dim3 tb(32, 8);
  wt_transpose<<<dim3(96, 32), tb, 0, stream>>>(w_qkv, wqkvT, 1024, 3072);
  wt_transpose<<<dim3(32, 32), tb, 0, stream>>>(w_proj, wprojT, 1024, 1024);
  wt_transpose<<<dim3(128, 32), tb, 0, stream>>>(w_fc1, wfc1T, 1024, 4096);
  wt_transpose<<<dim3(32, 128), tb, 0, stream>>>(w_fc2, wfc2T, 4096, 1024);

  ln_kernel<<<4096, 256, 0, stream>>>(x, ln1_g, ln1_b, lnb);

  gemm_kernel<128, 64, false, EP_QKV, 3><<<dim3(24, 32), 256, 0, stream>>>(
      lnb, wqkvT, b_qkv, 4096, 3072, 1024, (void*)qkvb, nullptr);

  attn_kernel<<<dim3(32, 32), 256, 0, stream>>>(qkvb, qkvb + 4194304, qkvb + 8388608, attnb);

  gemm_kernel<64, 64, true, EP_RES, 2><<<dim3(16, 32), 256, 0, stream>>>(
      attnb, wprojT, b_proj, 4096, 1024, 1024, (void*)x2, x);

  ln_kernel<<<4096, 256, 0, stream>>>(x2, ln2_g, ln2_b, lnb);

  gemm_kernel<128, 64, false, EP_GELU, 3><<<dim3(32, 32), 256, 0, stream>>>(
      lnb, wfc1T, b_fc1, 4096, 4096, 1024, (void*)hbuf, nullptr);

  gemm_kernel<64, 64, true, EP_RES, 2><<<dim3(16, 32), 256, 0, stream>>>(
      hbuf, wfc2T, b_fc2, 4096, 1024, 4096, d_out, x2);
}

// Round 10
// 315.022 us; speedup vs baseline: 1.0915x; 1.0063x over previous
//
#include <hip/hip_runtime.h>
#include <hip/hip_bf16.h>
#include <math.h>

typedef __bf16 bf16x8 __attribute__((ext_vector_type(8)));
typedef __bf16 bf16x4 __attribute__((ext_vector_type(4)));
typedef unsigned short u16x8 __attribute__((ext_vector_type(8)));
typedef float f32x4 __attribute__((ext_vector_type(4)));

#define EP_QKV 0
#define EP_GELU 1
#define EP_RES 2

static __device__ __forceinline__ unsigned short f2bf(float x) {
  unsigned int u = __float_as_uint(x);
  unsigned int r = (u + 0x7fffu + ((u >> 16) & 1u)) >> 16;  // RNE
  return (unsigned short)r;
}

// pack two fp32 -> two bf16 (truncation) in ONE v_perm_b32
static __device__ __forceinline__ unsigned int pkbf(float lo, float hi) {
  return __builtin_amdgcn_perm(__float_as_uint(hi), __float_as_uint(lo), 0x07060302);
}

static __device__ __forceinline__ void async16(const void* g, void* l) {
  __builtin_amdgcn_global_load_lds((__attribute__((address_space(1))) void*)g,
                                   (__attribute__((address_space(3))) void*)l, 16, 0, 0);
}

// ---------------- fused weight convert+transpose: all 4 weights, 1 launch ---
// fp32 [K][N] -> bf16 [N][K]; jobs flattened into one grid (saves 3 launch
// gaps; small jobs overlap CU-wise). Isolated retest: in R4 this was bundled
// with a spilling launch-bounds change; its own expectation is positive.
__global__ __launch_bounds__(256) void wt_all(
    const float* __restrict__ i0, unsigned short* __restrict__ o0,
    const float* __restrict__ i1, unsigned short* __restrict__ o1,
    const float* __restrict__ i2, unsigned short* __restrict__ o2,
    const float* __restrict__ i3, unsigned short* __restrict__ o3) {
  __shared__ float tile[32][33];
  const int b = blockIdx.x;
  const float* in; unsigned short* out; int K, N, nbx, lb;
  if (b < 3072)      { in = i0; out = o0; K = 1024; N = 3072; nbx = 96;  lb = b; }
  else if (b < 4096) { in = i1; out = o1; K = 1024; N = 1024; nbx = 32;  lb = b - 3072; }
  else if (b < 8192) { in = i2; out = o2; K = 1024; N = 4096; nbx = 128; lb = b - 4096; }
  else               { in = i3; out = o3; K = 4096; N = 1024; nbx = 32;  lb = b - 8192; }
  const int n0 = (lb % nbx) * 32;
  const int k0 = (lb / nbx) * 32;
  const int tx = threadIdx.x;  // 0..31
  const int ty = threadIdx.y;  // 0..7
  #pragma unroll
  for (int i = ty; i < 32; i += 8)
    tile[i][tx] = in[(size_t)(k0 + i) * N + n0 + tx];
  __syncthreads();
  #pragma unroll
  for (int i = ty; i < 32; i += 8)
    out[(size_t)(n0 + i) * K + k0 + tx] = f2bf(tile[tx][i]);
}

// ---------------- layernorm fp32 -> bf16 -----------------------------------
__global__ __launch_bounds__(256) void ln_kernel(const float* __restrict__ x,
                                                 const float* __restrict__ g,
                                                 const float* __restrict__ b,
                                                 unsigned short* __restrict__ outp) {
  const int row = blockIdx.x;
  const int tid = threadIdx.x;
  const int wave = tid >> 6, lane = tid & 63;
  const float4 v = ((const float4*)(x + (size_t)row * 1024))[tid];
  float s = v.x + v.y + v.z + v.w;
  #pragma unroll
  for (int i = 1; i < 64; i <<= 1) s += __shfl_xor(s, i);
  __shared__ float red[4];
  if (lane == 0) red[wave] = s;
  __syncthreads();
  const float mean = (red[0] + red[1] + red[2] + red[3]) * (1.f / 1024.f);
  const float dx = v.x - mean, dy = v.y - mean, dz = v.z - mean, dw = v.w - mean;
  float ss = dx * dx + dy * dy + dz * dz + dw * dw;
  #pragma unroll
  for (int i = 1; i < 64; i <<= 1) ss += __shfl_xor(ss, i);
  __syncthreads();
  if (lane == 0) red[wave] = ss;
  __syncthreads();
  const float var = (red[0] + red[1] + red[2] + red[3]) * (1.f / 1024.f);
  const float inv = rsqrtf(var + 1e-6f);
  const float4 gv = ((const float4*)g)[tid];
  const float4 bv = ((const float4*)b)[tid];
  ushort4 o;
  o.x = f2bf(dx * inv * gv.x + bv.x);
  o.y = f2bf(dy * inv * gv.y + bv.y);
  o.z = f2bf(dz * inv * gv.z + bv.z);
  o.w = f2bf(dw * inv * gv.w + bv.w);
  ((ushort4*)(outp + (size_t)row * 1024))[tid] = o;
}

// ---------------- GEMM: C = A[M,K] * BT[N,K]^T + bias ----------------------
// MODE is a TEMPLATE param (dead epilogues eliminated). MINW = min waves/SIMD.
// All single-buffer kernels at MINW=3 (proven; MINW=4 spills even with DCE —
// R7 vs R8 delta). DBUF kernels at 2 (grid-limited).
//  DBUF=false (m97-style): single 32KB LDS stage, issue -> sync -> compute ->
//    sync; latency hidden by CU-level block overlap (3 blocks/CU).
//  DBUF=true: double-buffered issue-ahead pipeline (TN=64 kernels, 2/CU).
// XCD-rectangle block swizzle in both: per-XCD L2 working set ~4-6 MB.
template <int TN, int BK, bool DBUF, int MODE, int MINW>
__global__ __launch_bounds__(256, MINW) void gemm_kernel(
    const unsigned short* __restrict__ A,   // bf16 [M][K]
    const unsigned short* __restrict__ BT,  // bf16 [N][K]
    const float* __restrict__ bias,         // [N]
    int M, int N, int K,
    void* __restrict__ outp, const float* __restrict__ res) {
  constexpr int AM = (TN == 128) ? 4 : 2;   // m-subtiles per wave
  constexpr int ACH = BK / 16;              // A chunks per lane per stage
  constexpr int BCH = TN * BK / 2048;       // B chunks per lane per stage
  constexpr int CPR = BK / 8;               // 16B chunks per LDS row
  constexpr int ABYTES = 256 * BK;          // A stage bytes (128 rows)
  constexpr int BBYTES = TN * BK * 2;
  constexpr int NBUF = DBUF ? 2 : 1;
  __shared__ __align__(16) char smem[NBUF * (ABYTES + BBYTES)];

  const int tid = threadIdx.x;
  const int wave = tid >> 6, lane = tid & 63;
  const int quad = lane >> 4, l16 = lane & 15;
  const int wm = (TN == 128) ? (wave >> 1) : wave;
  const int wn = (TN == 128) ? (wave & 1) : 0;

  // XCD-rectangle swizzle (requires nbm%4==0, nbn%2==0, grid%8==0)
  const int nbm = M >> 7, nbn = N / TN;
  const int lin = blockIdx.y * gridDim.x + blockIdx.x;
  const int g = lin & 7, idx = lin >> 3;
  const int gm = nbm >> 2, gn = nbn >> 1;
  const int bm = (g & 3) * gm + (idx % gm);
  const int bn = (g >> 2) * gn + (idx / gm);
  const int row_m = bm * 128, row_n = bn * TN;

  int ar[ACH], ac[ACH];
  #pragma unroll
  for (int i = 0; i < ACH; ++i) {
    const int c = wave * (64 * ACH) + i * 64 + lane;
    ar[i] = c / CPR;
    ac[i] = ((c % CPR) ^ (ar[i] & (CPR - 1))) * 8;
  }
  int br[BCH], bc[BCH];
  #pragma unroll
  for (int i = 0; i < BCH; ++i) {
    const int c = wave * (64 * BCH) + i * 64 + lane;
    br[i] = c / CPR;
    bc[i] = ((c % CPR) ^ (br[i] & (CPR - 1))) * 8;
  }

  const unsigned short* Ag = A + (size_t)row_m * K;
  const unsigned short* Bg = BT + (size_t)row_n * K;

  const f32x4 z = {0.f, 0.f, 0.f, 0.f};
  f32x4 acc[AM][4];
  #pragma unroll
  for (int i = 0; i < AM; ++i)
    #pragma unroll
    for (int j = 0; j < 4; ++j) acc[i][j] = z;

  auto issue = [&](int kt, int b) {
    unsigned short* As = (unsigned short*)(smem + b * ABYTES);
    unsigned short* Bs = (unsigned short*)(smem + NBUF * ABYTES + b * BBYTES);
    #pragma unroll
    for (int i = 0; i < ACH; ++i)
      async16(Ag + (size_t)ar[i] * K + kt + ac[i], As + wave * (ACH * 512) + i * 512);
    #pragma unroll
    for (int i = 0; i < BCH; ++i)
      async16(Bg + (size_t)br[i] * K + kt + bc[i], Bs + wave * (BCH * 512) + i * 512);
  };

  auto computeTile = [&](int b) {
    const unsigned short* As = (const unsigned short*)(smem + b * ABYTES);
    const unsigned short* Bs = (const unsigned short*)(smem + NBUF * ABYTES + b * BBYTES);
    #pragma unroll
    for (int h = 0; h < BK / 32; ++h) {
      bf16x8 af[AM], bfv[4];
      #pragma unroll
      for (int t = 0; t < AM; ++t) {
        const int row = wm * (AM * 16) + t * 16 + l16;
        const int ch = (h * 4 + quad) ^ (row & (CPR - 1));
        af[t] = *(const bf16x8*)(As + row * BK + ch * 8);
      }
      #pragma unroll
      for (int t = 0; t < 4; ++t) {
        const int row = wn * 64 + t * 16 + l16;
        const int ch = (h * 4 + quad) ^ (row & (CPR - 1));
        bfv[t] = *(const bf16x8*)(Bs + row * BK + ch * 8);
      }
      #pragma unroll
      for (int tm = 0; tm < AM; ++tm)
        #pragma unroll
        for (int tn = 0; tn < 4; ++tn)
          acc[tm][tn] = __builtin_amdgcn_mfma_f32_16x16x32_bf16(af[tm], bfv[tn], acc[tm][tn], 0, 0, 0);
    }
  };

  if constexpr (DBUF) {
    issue(0, 0);
    for (int kt = 0; kt < K; kt += BK) {
      const int b = (kt / BK) & 1;
      __syncthreads();  // drains issue(kt) — issued a full compute-phase ago
      if (kt + BK < K) issue(kt + BK, b ^ 1);
      computeTile(b);
    }
  } else {
    for (int kt = 0; kt < K; kt += BK) {
      issue(kt, 0);
      __syncthreads();  // implicit vmcnt(0) drain: stage resident
      computeTile(0);
      __syncthreads();  // all waves done reading before next overwrite
    }
  }

  // epilogue: C/D layout col = l16, row = quad*4 + reg
  #pragma unroll
  for (int tn = 0; tn < 4; ++tn) {
    const int col = row_n + wn * 64 + tn * 16 + l16;
    const float bv = bias[col];
    #pragma unroll
    for (int tm = 0; tm < AM; ++tm) {
      const int rbase = row_m + wm * (AM * 16) + tm * 16 + quad * 4;
      float v[4];
      #pragma unroll
      for (int r = 0; r < 4; ++r) v[r] = acc[tm][tn][r] + bv;
      if constexpr (MODE == EP_QKV) {
        unsigned short* outw = (unsigned short*)outp;
        const int which = col >> 10;
        const int h = (col >> 6) & 15, d = col & 63;
        const int bb = rbase >> 11, n = rbase & 2047;
        const size_t bh = (size_t)(bb * 16 + h);
        if (which == 0) {
          // Q pre-scaled by 0.125*log2(e) so softmax can use raw v_exp_f32
          #pragma unroll
          for (int r = 0; r < 4; ++r)
            outw[(bh * 2048 + n + r) * 64 + d] = f2bf(v[r] * 0.18033688011112043f);
        } else if (which == 1) {
          #pragma unroll
          for (int r = 0; r < 4; ++r)
            outw[4194304ull + (bh * 2048 + n + r) * 64 + d] = f2bf(v[r]);
        } else {
          uint2 o;
          o.x = pkbf(v[0], v[1]);
          o.y = pkbf(v[2], v[3]);
          *(uint2*)(outw + 8388608ull + (bh * 64 + d) * 2048 + n) = o;
        }
      } else if constexpr (MODE == EP_GELU) {
        #pragma unroll
        for (int r = 0; r < 4; ++r) {
          const float u = v[r];
          const float c = 1.5957691216f * fmaf(0.044715f * u * u, u, u);
          const float e = __expf(c);
          const float gl = u - __fdividef(u, e + 1.0f);
          ((unsigned short*)outp)[(size_t)(rbase + r) * N + col] = f2bf(gl);
        }
      } else {  // EP_RES
        #pragma unroll
        for (int r = 0; r < 4; ++r)
          ((float*)outp)[(size_t)(rbase + r) * N + col] =
              res[(size_t)(rbase + r) * N + col] + v[r];
      }
    }
  }
}

// ---------------- flash attention, key-split waves, fixed-shift softmax -----
// (R7 proven schedule, 53.3us.) LDS 48KB (Q direct-to-reg, single-buffered V).
// Per tile: sync -> issueV(t), issueK(t+1) -> QK+softmax -> {vmcnt(4);barrier}
// -> PV. Counted vmcnt keeps the K(t+1) prefetch in flight across the mid
// barrier; V latency hides under QK+softmax. R8's softmax-after-barrier was a
// real +1.4us regression (the pre-barrier softmax was hiding the V-wait) —
// reverted. Key-split retained: each K/V LDS fragment feeds 4 MFMA (q-split
// dropped reuse to 1/read, conflicts 4x, −12%). exp2 shift folded out
// (cancels in o*linv). setprio(1) around MFMA clusters.
__global__ __launch_bounds__(256, 3) void attn_kernel(
    const unsigned short* __restrict__ Q,   // [BH][2048][64] (scaled .125*log2e)
    const unsigned short* __restrict__ Kb,  // [BH][2048][64]
    const unsigned short* __restrict__ VT,  // [BH][64][2048]
    unsigned short* __restrict__ outp) {    // [B*2048][1024]
  __shared__ __align__(16) char smem[49152];
  unsigned short* Ks = (unsigned short*)smem;            // 2x [128][64] swz8 (16KB each)
  unsigned short* Vs = (unsigned short*)(smem + 32768);  // 1x [64][128] swz16 (16KB)

  const int tid = threadIdx.x;
  const int wave = tid >> 6, lane = tid & 63;
  const int quad = lane >> 4, l16 = lane & 15;

  // bhi-clustered XCD swizzle: XCD g (= lin&7, round-robin dispatch) owns
  // bhi in {4g..4g+3} -> per-XCD K+V working set ~1-1.5MB, L2-resident.
  // Requires grid == dim3(32, 32).
  const int lin = blockIdx.y * gridDim.x + blockIdx.x;
  const int g = lin & 7, idx = lin >> 3;        // g: XCD, idx: 0..127
  const int bhi = g * 4 + (idx >> 5);           // 4 bhi per XCD
  const int q0 = (idx & 31) * 64;               // 32 q-blocks per bhi

  const unsigned short* Qg = Q + ((size_t)bhi * 2048 + q0) * 64;
  const unsigned short* Kg = Kb + (size_t)bhi * 2048 * 64;
  const unsigned short* Vg = VT + (size_t)bhi * 64 * 2048;

  const unsigned short* kp[4];
  const unsigned short* vp[4];
  #pragma unroll
  for (int i = 0; i < 4; ++i) {
    const int c = wave * 256 + i * 64 + lane;
    const int krr = c >> 3, kcc = ((c & 7) ^ (krr & 7)) * 8;
    const int vrr = c >> 4, vcc = ((c & 15) ^ (vrr & 15)) * 8;
    kp[i] = Kg + (size_t)krr * 64 + kcc;
    vp[i] = Vg + (size_t)vrr * 2048 + vcc;
  }

  auto issueK = [&](int b) {
    unsigned short* Kd = Ks + b * 8192;
    #pragma unroll
    for (int i = 0; i < 4; ++i) async16(kp[i], Kd + wave * 2048 + i * 512);
    #pragma unroll
    for (int i = 0; i < 4; ++i) kp[i] += 8192;
  };
  auto issueV = [&]() {
    #pragma unroll
    for (int i = 0; i < 4; ++i) async16(vp[i], Vs + wave * 2048 + i * 512);
    #pragma unroll
    for (int i = 0; i < 4; ++i) vp[i] += 128;
  };

  issueK(0);

  // Q fragments straight from global (L2-warm): row nt*16+l16, 16B chunk
  // (h*4+quad) — same data the old LDS stage delivered, minus the round-trip.
  bf16x8 qb[4][2];
  #pragma unroll
  for (int nt = 0; nt < 4; ++nt)
    #pragma unroll
    for (int h = 0; h < 2; ++h)
      qb[nt][h] = *(const bf16x8*)(Qg + (nt * 16 + l16) * 64 + (h * 4 + quad) * 8);

  const f32x4 z = {0.f, 0.f, 0.f, 0.f};
  f32x4 acc[4][4];
  #pragma unroll
  for (int i = 0; i < 4; ++i)
    #pragma unroll
    for (int j = 0; j < 4; ++j) acc[i][j] = z;
  float lsum[4] = {0.f, 0.f, 0.f, 0.f};

  const int rowA = wave * 16 + l16;
  const int rowB = 64 + rowA;
  const int swk = l16 & 7;

  bf16x8 pb[4];
  auto computeQK = [&](int b) {
    const unsigned short* Ksb = Ks + b * 8192;
    f32x4 sA[4], sB[4];
    #pragma unroll
    for (int nt = 0; nt < 4; ++nt) { sA[nt] = z; sB[nt] = z; }
    __builtin_amdgcn_s_setprio(1);
    #pragma unroll
    for (int h = 0; h < 2; ++h) {
      const int ch = (h * 4 + quad) ^ swk;
      bf16x8 kfA = *(const bf16x8*)(Ksb + rowA * 64 + ch * 8);
      bf16x8 kfB = *(const bf16x8*)(Ksb + rowB * 64 + ch * 8);
      #pragma unroll
      for (int nt = 0; nt < 4; ++nt) {
        sA[nt] = __builtin_amdgcn_mfma_f32_16x16x32_bf16(kfA, qb[nt][h], sA[nt], 0, 0, 0);
        sB[nt] = __builtin_amdgcn_mfma_f32_16x16x32_bf16(kfB, qb[nt][h], sB[nt], 0, 0, 0);
      }
    }
    __builtin_amdgcn_s_setprio(0);
    #pragma unroll
    for (int nt = 0; nt < 4; ++nt) {
      union { unsigned int d[4]; bf16x8 b; } cv;
      float pa[4], pv[4];
      float ls = 0.f;
      #pragma unroll
      for (int r = 0; r < 4; ++r) {
        pa[r] = __builtin_amdgcn_exp2f(sA[nt][r]);
        pv[r] = __builtin_amdgcn_exp2f(sB[nt][r]);
        ls += pa[r] + pv[r];
      }
      cv.d[0] = pkbf(pa[0], pa[1]);
      cv.d[1] = pkbf(pa[2], pa[3]);
      cv.d[2] = pkbf(pv[0], pv[1]);
      cv.d[3] = pkbf(pv[2], pv[3]);
      lsum[nt] += ls;
      pb[nt] = cv.b;
    }
  };

  auto computePV = [&]() {
    __builtin_amdgcn_s_setprio(1);
    #pragma unroll
    for (int mt = 0; mt < 4; ++mt) {
      const int d = mt * 16 + l16;
      const int cA = (wave * 2 + (quad >> 1)) ^ (d & 15);
      const int cB = (8 + wave * 2 + (quad >> 1)) ^ (d & 15);
      const int sub = (quad & 1) * 4;
      bf16x4 vA = *(const bf16x4*)(Vs + d * 128 + cA * 8 + sub);
      bf16x4 vB = *(const bf16x4*)(Vs + d * 128 + cB * 8 + sub);
      bf16x8 vf = __builtin_shufflevector(vA, vB, 0, 1, 2, 3, 4, 5, 6, 7);
      #pragma unroll
      for (int nt = 0; nt < 4; ++nt)
        acc[mt][nt] = __builtin_amdgcn_mfma_f32_16x16x32_bf16(vf, pb[nt], acc[mt][nt], 0, 0, 0);
    }
    __builtin_amdgcn_s_setprio(0);
  };

  for (int t = 0; t < 16; ++t) {
    __syncthreads();            // K(t) resident; all waves done with Vs(t-1)
    issueV();                   // 4 loads/wave -> Vs
    issueK((t + 1) & 1);        // 4 loads/wave -> other K buffer (t=15: harmless
                                // in-bounds prefetch of the adjacent region)
    computeQK(t & 1);
    // wait the 4 V loads only; K(t+1) prefetch stays in flight across barrier
    asm volatile("s_waitcnt vmcnt(4) lgkmcnt(0)\n\ts_barrier" ::: "memory");
    computePV();
  }
  __syncthreads();

  float* sc = (float*)smem;
  float* lred = (float*)(smem + 32768);
  #pragma unroll
  for (int nt = 0; nt < 4; ++nt) {
    float ls = lsum[nt];
    ls += __shfl_xor(ls, 16);
    ls += __shfl_xor(ls, 32);
    if (quad == 0) lred[wave * 64 + nt * 16 + l16] = ls;
  }
  if (wave >= 2) {
    float* dst = sc + (wave - 2) * 4096;
    #pragma unroll
    for (int mt = 0; mt < 4; ++mt)
      #pragma unroll
      for (int nt = 0; nt < 4; ++nt)
        *(f32x4*)(dst + (mt * 4 + nt) * 256 + lane * 4) = acc[mt][nt];
  }
  __syncthreads();
  if (wave < 2) {
    const float* src = sc + wave * 4096;
    #pragma unroll
    for (int mt = 0; mt < 4; ++mt)
      #pragma unroll
      for (int nt = 0; nt < 4; ++nt)
        acc[mt][nt] += *(const f32x4*)(src + (mt * 4 + nt) * 256 + lane * 4);
  }
  if (wave == 1) {
    float* dst = sc + 4096;
    #pragma unroll
    for (int mt = 0; mt < 4; ++mt)
      #pragma unroll
      for (int nt = 0; nt < 4; ++nt)
        *(f32x4*)(dst + (mt * 4 + nt) * 256 + lane * 4) = acc[mt][nt];
  }
  __syncthreads();
  if (wave == 0) {
    const float* src = sc + 4096;
    float linv[4];
    #pragma unroll
    for (int nt = 0; nt < 4; ++nt) {
      const int qi = nt * 16 + l16;
      const float l = lred[qi] + lred[64 + qi] + lred[128 + qi] + lred[192 + qi];
      linv[nt] = 1.0f / l;
    }
    const int b = bhi >> 4, h = bhi & 15;
    #pragma unroll
    for (int mt = 0; mt < 4; ++mt)
      #pragma unroll
      for (int nt = 0; nt < 4; ++nt) {
        f32x4 o = acc[mt][nt] + *(const f32x4*)(src + (mt * 4 + nt) * 256 + lane * 4);
        uint2 ov;
        ov.x = pkbf(o[0] * linv[nt], o[1] * linv[nt]);
        ov.y = pkbf(o[2] * linv[nt], o[3] * linv[nt]);
        *(uint2*)(outp + ((size_t)(b * 2048 + q0 + nt * 16 + l16)) * 1024 +
                  h * 64 + mt * 16 + quad * 4) = ov;
      }
  }
}

// ---------------- launch -----------------------------------------------------
extern "C" void kernel_launch(void* const* d_in, const int* in_sizes, int n_in,
                              void* d_out, int out_size, void* d_ws, size_t ws_size,
                              hipStream_t stream) {
  (void)in_sizes; (void)n_in; (void)out_size; (void)ws_size;
  const float* x      = (const float*)d_in[0];
  const float* ln1_g  = (const float*)d_in[1];
  const float* ln1_b  = (const float*)d_in[2];
  const float* w_qkv  = (const float*)d_in[3];
  const float* b_qkv  = (const float*)d_in[4];
  const float* w_proj = (const float*)d_in[5];
  const float* b_proj = (const float*)d_in[6];
  const float* ln2_g  = (const float*)d_in[7];
  const float* ln2_b  = (const float*)d_in[8];
  const float* w_fc1  = (const float*)d_in[9];
  const float* b_fc1  = (const float*)d_in[10];
  const float* w_fc2  = (const float*)d_in[11];
  const float* b_fc2  = (const float*)d_in[12];

  char* ws = (char*)d_ws;
  unsigned short* wqkvT  = (unsigned short*)(ws + 0);
  unsigned short* wprojT = (unsigned short*)(ws + 6291456);
  unsigned short* wfc1T  = (unsigned short*)(ws + 8388608);
  unsigned short* wfc2T  = (unsigned short*)(ws + 16777216);
  unsigned short* lnb    = (unsigned short*)(ws + 25165824);
  unsigned short* qkvb   = (unsigned short*)(ws + 33554432);
  unsigned short* attnb  = (unsigned short*)(ws + 58720256);
  float*          x2     = (float*)(ws + 67108864);
  unsigned short* hbuf   = qkvb;  // fc1 out aliases dead qkv region

  wt_all<<<12288, dim3(32, 8), 0, stream>>>(w_qkv, wqkvT, w_proj, wprojT,
                                            w_fc1, wfc1T, w_fc2, wfc2T);

  ln_kernel<<<4096, 256, 0, stream>>>(x, ln1_g, ln1_b, lnb);

  gemm_kernel<128, 64, false, EP_QKV, 3><<<dim3(24, 32), 256, 0, stream>>>(
      lnb, wqkvT, b_qkv, 4096, 3072, 1024, (void*)qkvb, nullptr);

  attn_kernel<<<dim3(32, 32), 256, 0, stream>>>(qkvb, qkvb + 4194304, qkvb + 8388608, attnb);

  gemm_kernel<64, 64, true, EP_RES, 2><<<dim3(16, 32), 256, 0, stream>>>(
      attnb, wprojT, b_proj, 4096, 1024, 1024, (void*)x2, x);

  ln_kernel<<<4096, 256, 0, stream>>>(x2, ln2_g, ln2_b, lnb);

  gemm_kernel<128, 64, false, EP_GELU, 3><<<dim3(32, 32), 256, 0, stream>>>(
      lnb, wfc1T, b_fc1, 4096, 4096, 1024, (void*)hbuf, nullptr);

  gemm_kernel<64, 64, true, EP_RES, 2><<<dim3(16, 32), 256, 0, stream>>>(
      hbuf, wfc2T, b_fc2, 4096, 1024, 4096, d_out, x2);
}